// Round 4
// baseline (1019.308 us; speedup 1.0000x reference)
//
#include <hip/hip_runtime.h>
#include <hip/hip_bf16.h>
#include <stdint.h>

#define N_PTS   262144
#define H_DIM   512
#define W_DIM   512
#define N_SEG   16
#define EPS_V   1e-5f

typedef __bf16 bf16_t;
typedef __bf16 bf16x8 __attribute__((ext_vector_type(8)));
typedef float  f32x4  __attribute__((ext_vector_type(4)));

// async global->LDS, 16B per lane. LDS dest must be wave-uniform base + lane*16.
__device__ __forceinline__ void gl_lds16(const bf16_t* g, bf16_t* l) {
  __builtin_amdgcn_global_load_lds(
      (const __attribute__((address_space(1))) unsigned int*)g,
      (__attribute__((address_space(3))) unsigned int*)l, 16, 0, 0);
}

// ------------- workspace layouts -------------
// T2 SORTED (ws >= 141.2 MB):
//   idx_map int[4*512*512]  @ 0          (seg<<18)|sorted_pos, -1 empty
//   cat     bf16[(N+1)*256] @ 4194304    SORTED rows: cat[pos] = point ord[pos]
//   wfrag   bf16[258048]    @ 138412544
//   stats   float[12416]    @ 138928640
//   hist    int[4096]       @ 138978304
//   cursor  int[4096]       @ 138994688
//   ord     int[N]          @ 139011072  sorted pos -> original idx
//   meta    int[N]          @ 140059648  (seg<<20)|(b<<18)|(y<<9)|x per sorted pos
// T1 FUSED (ws >= 139 MB): round-3 layout, unsorted (ord=nullptr)
// T0 FALLBACK: 64-ch buffers at 72 MB.
// stats block (floats): cnt[16]@0 ymin@16 ymax@32 xmin@48 xmax@64 dseg[48]@80
//   sums[3*1024]@128 sumsq[3*1024]@3200 pA[3*1024]@6272 pB[3*1024]@9344

__global__ void init_kernel(int* cnt, int* ymin, int* ymax, int* xmin, int* xmax,
                            float* sums, float* sumsq, int* hist) {
  int t = threadIdx.x;
  if (t < N_SEG) {
    cnt[t] = 0;
    ymin[t] = 0x7fffffff; ymax[t] = (int)0x80000000;
    xmin[t] = 0x7fffffff; xmax[t] = (int)0x80000000;
  }
  for (int i = t; i < 3 * 1024; i += 256) { sums[i] = 0.f; sumsq[i] = 0.f; }
  if (hist) for (int i = t; i < 4096; i += 256) hist[i] = 0;
}

__global__ void scatter_kernel(const int* __restrict__ indices,
                               const int* __restrict__ seg,
                               int* __restrict__ idx_map,
                               int* __restrict__ cnt,
                               int* __restrict__ ymin, int* __restrict__ ymax,
                               int* __restrict__ xmin, int* __restrict__ xmax,
                               int* __restrict__ hist) {
  __shared__ int lc[N_SEG], ly0[N_SEG], ly1[N_SEG], lx0[N_SEG], lx1[N_SEG];
  int tid = threadIdx.x;
  if (tid < N_SEG) {
    lc[tid] = 0;
    ly0[tid] = 0x7fffffff; ly1[tid] = (int)0x80000000;
    lx0[tid] = 0x7fffffff; lx1[tid] = (int)0x80000000;
  }
  __syncthreads();
  int i = blockIdx.x * 256 + tid;
  int b = indices[i * 3], y = indices[i * 3 + 1], x = indices[i * 3 + 2];
  int s = seg[i];
  idx_map[(b * H_DIM + y) * W_DIM + x] = (s << 18) | i;   // T1 packing; T2 overwrites in rank
  atomicAdd(&lc[s], 1);
  atomicMin(&ly0[s], y); atomicMax(&ly1[s], y);
  atomicMin(&lx0[s], x); atomicMax(&lx1[s], x);
  if (hist) {
    int key = (b << 10) | ((y >> 4) << 5) | (x >> 4);     // 4096 spatial tiles
    atomicAdd(&hist[key], 1);
  }
  __syncthreads();
  if (tid < N_SEG && lc[tid] > 0) {
    atomicAdd(&cnt[tid], lc[tid]);
    atomicMin(&ymin[tid], ly0[tid]); atomicMax(&ymax[tid], ly1[tid]);
    atomicMin(&xmin[tid], lx0[tid]); atomicMax(&xmax[tid], lx1[tid]);
  }
}

// exclusive prefix sum of hist[4096] -> cursor[4096]
__global__ void scan_kernel(const int* __restrict__ hist, int* __restrict__ cursor) {
  __shared__ int s[256];
  int t = threadIdx.x;
  int base = t * 16;
  int loc[16];
  int acc = 0;
#pragma unroll
  for (int j = 0; j < 16; ++j) { loc[j] = acc; acc += hist[base + j]; }
  s[t] = acc;
  __syncthreads();
  for (int o = 1; o < 256; o <<= 1) {
    int v = (t >= o) ? s[t - o] : 0;
    __syncthreads();
    s[t] += v;
    __syncthreads();
  }
  int pre = (t == 0) ? 0 : s[t - 1];
#pragma unroll
  for (int j = 0; j < 16; ++j) cursor[base + j] = pre + loc[j];
}

// T2 rank: assigns sorted pos; writes ord, packed meta, and pos-packed idx_map
__global__ void rank_kernel(const int* __restrict__ indices,
                            const int* __restrict__ seg,
                            int* __restrict__ cursor, int* __restrict__ ord,
                            int* __restrict__ meta, int* __restrict__ idx_map) {
  int i = blockIdx.x * 256 + threadIdx.x;
  int b = indices[i * 3], y = indices[i * 3 + 1], x = indices[i * 3 + 2];
  int key = (b << 10) | ((y >> 4) << 5) | (x >> 4);
  int pos = atomicAdd(&cursor[key], 1);
  int s = seg[i];
  ord[pos] = i;
  meta[pos] = (s << 20) | (b << 18) | (y << 9) | x;
  idx_map[(b * H_DIM + y) * W_DIM + x] = (s << 18) | pos;
}

__global__ void dilation_kernel(const int* ymin, const int* ymax,
                                const int* xmin, const int* xmax,
                                const int* cnt, int* dseg) {
  int t = threadIdx.x;
  if (t < 48) {
    int r = t >> 4, s = t & 15;
    int rate = (r == 0) ? 1 : (r == 1) ? 3 : 5;
    int d = 1;
    if (cnt[s] > 0) {
      float hr = (float)(ymax[s] - ymin[s]) * (1.0f / H_DIM);
      float wr = (float)(xmax[s] - xmin[s]) * (1.0f / W_DIM);
      d = (int)ceilf(fmaxf(hr, wr) * (float)rate);
      if (d < 1) d = 1;
    }
    dseg[t] = d;
  }
}

// features fp32 -> bf16 rows; dst row pt <- src row (ord? ord[pt] : pt)
__global__ void convert_kernel(const float4* __restrict__ in, bf16_t* __restrict__ dst,
                               int stride, const int* __restrict__ ord) {
  int i = blockIdx.x * 256 + threadIdx.x;   // N*16
  int pt = i >> 4, g = i & 15;
  int sp = ord ? ord[pt] : pt;
  float4 v = in[(size_t)sp * 16 + g];
  union { bf16_t h[4]; uint2 u; } o;
  o.h[0] = (bf16_t)v.x; o.h[1] = (bf16_t)v.y;
  o.h[2] = (bf16_t)v.z; o.h[3] = (bf16_t)v.w;
  *(uint2*)(dst + (size_t)pt * stride + g * 4) = o.u;
}

// wfrag: [0,110592): branch r in {0,1,2} at r*36864, layout [k][kk2][cot][lane][j]
//        [110592,258048): fused final, layout [k][kk8][cot][lane][j], kk8=0..7
__global__ void repack_kernel(const float* __restrict__ w1, const float* __restrict__ w2,
                              const float* __restrict__ w3, const float* __restrict__ wf,
                              bf16_t* __restrict__ wfrag) {
  int e = blockIdx.x * 256 + threadIdx.x;   // < 258048
  if (e < 110592) {
    int s = e / 36864, rem = e % 36864;
    int k = rem >> 12, r2 = rem & 4095;
    int kk = r2 >> 11, r3 = r2 & 2047;
    int cot = r3 >> 9, r4 = r3 & 511;
    int lane = r4 >> 3, j = r4 & 7;
    int c  = kk * 32 + (lane >> 4) * 8 + j;
    int co = cot * 16 + (lane & 15);
    const float* w = (s == 0) ? w1 : (s == 1) ? w2 : w3;
    wfrag[e] = (bf16_t)w[k * 4096 + c * 64 + co];
  } else {
    int ef = e - 110592;
    int k = ef >> 14, r2 = ef & 16383;
    int kk8 = r2 >> 11, r3 = r2 & 2047;
    int cot = r3 >> 9, r4 = r3 & 511;
    int lane = r4 >> 3, j = r4 & 7;
    int c  = kk8 * 32 + (lane >> 4) * 8 + j;   // 0..255
    int co = cot * 16 + (lane & 15);
    wfrag[e] = (bf16_t)wf[k * 16384 + c * 64 + co];
  }
}

#define MF(ar, wr, i, j) \
  acc[i][j] = __builtin_amdgcn_mfma_f32_16x16x32_bf16(ar, wr, acc[i][j], 0, 0, 0)

// ============ T2 sorted conv ============
// cat rows are tile-sorted: a block's 256 points are rows [pt0, pt0+256) --
// contiguous. Block stages its OWN rows into LDS (coalesced, zero-redundancy
// global_load_lds, 16B-piece XOR swizzle via pre-swizzled global source);
// tap reads are LDS for in-block neighbors (~85% at d=1; center tap always)
// with a masked global fallback (sentinel-merged). Outputs go through an LDS
// transpose-bounce to coalesced 16B/lane stores. This attacks the measured
// bottleneck: per-CU vector-memory address processing (~4cy per distinct
// 128B line per instruction), not bandwidth.
// KK=2: branch conv (64ch, seg mask + dilation) -> bf16 slice at hoff
// KK=8: final conv (256ch, 4 quarter-K passes) -> float out rows via ord
template <int KK, int MODE>
__launch_bounds__(256, 2)
__global__ void conv_sorted(const bf16_t* __restrict__ A,
                            const bf16_t* __restrict__ wfrag, int wkstride,
                            const int* __restrict__ meta,
                            const int* __restrict__ idx_map,
                            const int* __restrict__ dseg,
                            const int* __restrict__ ord,
                            float* __restrict__ outf,
                            bf16_t* __restrict__ outh, int hoff,
                            const float* __restrict__ bias) {
  __shared__ __align__(16) bf16_t s_a[256 * 64];   // 32 KB
  __shared__ __align__(16) bf16_t s_w[2][4096];    // 16 KB dbuf
  __shared__ int s_nbr[9 * 256];
  __shared__ int s_pt[256];
  const int tid = threadIdx.x;
  int bid = blockIdx.x;
  bid = (bid & 7) * ((int)gridDim.x >> 3) + (bid >> 3);   // XCD swizzle (1024%8==0)
  const int pt0 = bid * 256;

  // ---- setup: coalesced meta, spatially-local idx_map gathers ----
  {
    int mt = meta[pt0 + tid];
    if (MODE == 1) s_pt[tid] = ord[pt0 + tid];
    int sg = mt >> 20;
    int b = (mt >> 18) & 3, y = (mt >> 9) & 511, x = mt & 511;
    int d = (MODE == 0) ? dseg[sg] : 1;
#pragma unroll
    for (int k = 0; k < 9; ++k) {
      int ky = (k / 3) - 1, kx = (k % 3) - 1;
      int ny = y + ky * d, nx = x + kx * d;
      int e = N_PTS;                           // sentinel zero row
      if (ny >= 0 && ny < H_DIM && nx >= 0 && nx < W_DIM) {
        int v = idx_map[(b * H_DIM + ny) * W_DIM + nx];
        if (v >= 0) {
          int pos2 = v & 0x3FFFF;
          if (MODE == 0) { if ((v >> 18) == sg) e = pos2; }
          else e = pos2;
        }
      }
      unsigned lo = (unsigned)(e - pt0);
      s_nbr[k * 256 + tid] = (lo < 256u) ? -(int)(lo + 1) : e;   // neg = local slot
    }
  }

  const int lane = tid & 63;
  const int wv = tid >> 6;
  const int m = lane & 15;
  const int quad = lane >> 4;
  const int rb = wv * 64 + m;

  float b4[4];
  if (MODE == 1) {
#pragma unroll
    for (int cot = 0; cot < 4; ++cot) b4[cot] = bias[cot * 16 + m];
  }

  // stage own rows, quarter q (64ch = 8 x 16B pieces per row), piece-XOR-swizzled
  auto stageA = [&](int q) {
#pragma unroll
    for (int s = 0; s < 8; ++s) {
      int ch = s * 256 + tid;
      int r = ch >> 3, p = ch & 7;
      int ps = p ^ (r & 7);
      gl_lds16(A + (size_t)(pt0 + r) * 256 + q * 64 + ps * 8, &s_a[ch * 8]);
    }
  };
  auto stageW = [&](int k, int q, int buf) {
    const bf16_t* src = wfrag + (size_t)k * wkstride + q * 4096;
#pragma unroll
    for (int s = 0; s < 2; ++s) {
      int off = s * 2048 + tid * 8;
      gl_lds16(src + off, &s_w[buf][off]);
    }
  };

  f32x4 acc[4][4];
#pragma unroll
  for (int rt = 0; rt < 4; ++rt)
#pragma unroll
    for (int c = 0; c < 4; ++c) {
      acc[rt][c][0] = 0.f; acc[rt][c][1] = 0.f;
      acc[rt][c][2] = 0.f; acc[rt][c][3] = 0.f;
    }

  constexpr int NQ = (KK == 8) ? 4 : 1;
  for (int q = 0; q < NQ; ++q) {
    __syncthreads();                   // prev-quarter readers done / setup visible
    stageA(q);
    stageW(0, q, 0);
    __syncthreads();                   // drains vmcnt: s_a + s_w[0] ready
    int buf = 0;
    for (int k = 0; k < 9; ++k) {
      if (k < 8) stageW(k + 1, q, buf ^ 1);
      const int* sn = s_nbr + k * 256;
#pragma unroll
      for (int rt = 0; rt < 4; ++rt) {
        int e = sn[rb + rt * 16];
        bool loc = e < 0;
        int slot = loc ? (-e - 1) : 0;
        int grow = loc ? N_PTS : e;
        const bf16_t* gp = A + (size_t)grow * 256 + q * 64 + quad * 8;
        bf16x8 g0 = *(const bf16x8*)(gp);
        bf16x8 g1 = *(const bf16x8*)(gp + 32);
        int sw = slot & 7;
        bf16x8 l0 = *(const bf16x8*)&s_a[slot * 64 + ((quad ^ sw) << 3)];
        bf16x8 l1 = *(const bf16x8*)&s_a[slot * 64 + (((4 + quad) ^ sw) << 3)];
        bf16x8 a0 = loc ? l0 : g0;
        bf16x8 a1 = loc ? l1 : g1;
        const bf16_t* wl = &s_w[buf][lane * 8];
        MF(a0, *(const bf16x8*)(wl +    0), rt, 0);
        MF(a0, *(const bf16x8*)(wl +  512), rt, 1);
        MF(a0, *(const bf16x8*)(wl + 1024), rt, 2);
        MF(a0, *(const bf16x8*)(wl + 1536), rt, 3);
        MF(a1, *(const bf16x8*)(wl + 2048), rt, 0);
        MF(a1, *(const bf16x8*)(wl + 2560), rt, 1);
        MF(a1, *(const bf16x8*)(wl + 3072), rt, 2);
        MF(a1, *(const bf16x8*)(wl + 3584), rt, 3);
      }
      __syncthreads();                 // all done with s_w[buf]; next stage landed
      buf ^= 1;
    }
  }

  // ---- epilogue via LDS bounce -> coalesced stores ----
  if (MODE == 0) {
#pragma unroll
    for (int rt = 0; rt < 4; ++rt)
#pragma unroll
      for (int reg = 0; reg < 4; ++reg) {
        int row = wv * 64 + rt * 16 + quad * 4 + reg;
#pragma unroll
        for (int cot = 0; cot < 4; ++cot) {
          int col = cot * 16 + m;
          int p = col >> 3;
          s_a[row * 64 + (((p ^ (row & 7)) << 3) | (col & 7))] = (bf16_t)acc[rt][cot][reg];
        }
      }
    __syncthreads();
#pragma unroll
    for (int s = 0; s < 8; ++s) {
      int g = s * 256 + tid;
      int r = g >> 3, p = g & 7;
      uint4 v = *(const uint4*)&s_a[r * 64 + ((p ^ (r & 7)) << 3)];
      *(uint4*)(outh + (size_t)(pt0 + r) * 256 + hoff + p * 8) = v;
    }
  } else {
    float* s_af = (float*)s_a;         // 256 x 32 f32 per half
#pragma unroll
    for (int hh = 0; hh < 2; ++hh) {
      if (hh) __syncthreads();
#pragma unroll
      for (int rt = 0; rt < 4; ++rt)
#pragma unroll
        for (int reg = 0; reg < 4; ++reg) {
          int row = wv * 64 + rt * 16 + quad * 4 + reg;
#pragma unroll
          for (int c2 = 0; c2 < 2; ++c2) {
            int cot = hh * 2 + c2;
            int col32 = c2 * 16 + m;
            int p = col32 >> 2;
            s_af[row * 32 + (((p ^ (row & 7)) << 2) | (col32 & 3))] =
                acc[rt][cot][reg] + b4[cot];
          }
        }
      __syncthreads();
#pragma unroll
      for (int s = 0; s < 8; ++s) {
        int g = s * 256 + tid;
        int r = g >> 3, p = g & 7;
        float4 v = *(const float4*)&s_af[r * 32 + ((p ^ (r & 7)) << 2)];
        *(float4*)(outf + (size_t)s_pt[r] * 64 + hh * 32 + p * 4) = v;
      }
    }
  }
}

// ============ T1/T0 conv (round-3 version, unsorted-safe) ============
template <int KK, int MODE>
__launch_bounds__(256, 3)
__global__ void conv_mfma(const bf16_t* __restrict__ A, int astride,
                          const bf16_t* __restrict__ wfrag, int wkstride,
                          const int* __restrict__ indices,
                          const int* __restrict__ seg,
                          const int* __restrict__ idx_map,
                          const int* __restrict__ dseg,
                          float* __restrict__ outf,
                          bf16_t* __restrict__ outh, int hstride, int hoff,
                          const float* __restrict__ bias) {
  constexpr int WELEM = (KK == 8) ? 8192 : 4096;
  constexpr int SWEEPS = (KK == 8) ? 4 : 2;
  __shared__ int s_nbr[9 * 256];
  __shared__ __align__(16) bf16_t s_w[2][WELEM];
  const int tid = threadIdx.x;
  const int pt0 = blockIdx.x * 256;

  {
    int pt = pt0 + tid;
    int b = indices[pt * 3], y = indices[pt * 3 + 1], x = indices[pt * 3 + 2];
    int sg = 0, d = 1;
    if (MODE == 0) { sg = seg[pt]; d = dseg[sg]; }
#pragma unroll
    for (int k = 0; k < 9; ++k) {
      int ky = (k / 3) - 1, kx = (k % 3) - 1;
      int ny = y + ky * d, nx = x + kx * d;
      int nbr = N_PTS;
      if (ny >= 0 && ny < H_DIM && nx >= 0 && nx < W_DIM) {
        int v = idx_map[(b * H_DIM + ny) * W_DIM + nx];
        if (v >= 0) {
          if (MODE == 0) nbr = ((v >> 18) == sg) ? (v & 0x3FFFF) : N_PTS;
          else           nbr = v & 0x3FFFF;
        }
      }
      s_nbr[k * 256 + tid] = nbr;
    }
  }

  auto stage = [&](int ph, int buf) {
    const bf16_t* src;
    if constexpr (KK == 8) src = wfrag + (size_t)(ph >> 1) * wkstride + (ph & 1) * 8192;
    else                   src = wfrag + (size_t)ph * wkstride;
#pragma unroll
    for (int s = 0; s < SWEEPS; ++s) {
      int off = s * 2048 + tid * 8;
      gl_lds16(src + off, &s_w[buf][off]);
    }
  };

  stage(0, 0);
  __syncthreads();

  const int lane = tid & 63;
  const int wv = tid >> 6;
  const int m = lane & 15;
  const int quad = lane >> 4;
  const int rbase = wv * 64 + m;

  f32x4 acc[4][4];
#pragma unroll
  for (int rt = 0; rt < 4; ++rt)
#pragma unroll
    for (int c = 0; c < 4; ++c) {
      acc[rt][c][0] = 0.f; acc[rt][c][1] = 0.f;
      acc[rt][c][2] = 0.f; acc[rt][c][3] = 0.f;
    }

#define MF16X(A0, A1, A2, A3, W0, W1, W2, W3) \
  MF(A0, W0, 0, 0); MF(A0, W1, 0, 1); MF(A0, W2, 0, 2); MF(A0, W3, 0, 3); \
  MF(A1, W0, 1, 0); MF(A1, W1, 1, 1); MF(A1, W2, 1, 2); MF(A1, W3, 1, 3); \
  MF(A2, W0, 2, 0); MF(A2, W1, 2, 1); MF(A2, W2, 2, 2); MF(A2, W3, 2, 3); \
  MF(A3, W0, 3, 0); MF(A3, W1, 3, 1); MF(A3, W2, 3, 2); MF(A3, W3, 3, 3)

  if constexpr (KK == 2) {
    for (int k = 0; k < 9; ++k) {
      const int cur = k & 1;
      if (k < 8) stage(k + 1, cur ^ 1);
      const int* sn = s_nbr + k * 256 + rbase;
      const bf16_t* a0p = A + (size_t)sn[0]  * astride + quad * 8;
      const bf16_t* a1p = A + (size_t)sn[16] * astride + quad * 8;
      const bf16_t* a2p = A + (size_t)sn[32] * astride + quad * 8;
      const bf16_t* a3p = A + (size_t)sn[48] * astride + quad * 8;
      bf16x8 a00 = *(const bf16x8*)(a0p), a01 = *(const bf16x8*)(a0p + 32);
      bf16x8 a10 = *(const bf16x8*)(a1p), a11 = *(const bf16x8*)(a1p + 32);
      bf16x8 a20 = *(const bf16x8*)(a2p), a21 = *(const bf16x8*)(a2p + 32);
      bf16x8 a30 = *(const bf16x8*)(a3p), a31 = *(const bf16x8*)(a3p + 32);
      const bf16_t* wl = &s_w[cur][lane * 8];
      bf16x8 w00 = *(const bf16x8*)(wl +    0), w01 = *(const bf16x8*)(wl +  512);
      bf16x8 w02 = *(const bf16x8*)(wl + 1024), w03 = *(const bf16x8*)(wl + 1536);
      bf16x8 w10 = *(const bf16x8*)(wl + 2048), w11 = *(const bf16x8*)(wl + 2560);
      bf16x8 w12 = *(const bf16x8*)(wl + 3072), w13 = *(const bf16x8*)(wl + 3584);
      MF16X(a00, a10, a20, a30, w00, w01, w02, w03);
      MF16X(a01, a11, a21, a31, w10, w11, w12, w13);
      __syncthreads();
    }
  } else {
    for (int h = 0; h < 18; ++h) {
      const int cur = h & 1;
      if (h < 17) stage(h + 1, cur ^ 1);
      const int k = h >> 1;
      const int colb = (h & 1) * 128;
      const int* sn = s_nbr + k * 256 + rbase;
      const bf16_t* a0p = A + (size_t)sn[0]  * astride + quad * 8 + colb;
      const bf16_t* a1p = A + (size_t)sn[16] * astride + quad * 8 + colb;
      const bf16_t* a2p = A + (size_t)sn[32] * astride + quad * 8 + colb;
      const bf16_t* a3p = A + (size_t)sn[48] * astride + quad * 8 + colb;
#pragma unroll
      for (int kp = 0; kp < 2; ++kp) {
        const int cb = kp * 64;
        bf16x8 a00 = *(const bf16x8*)(a0p + cb), a01 = *(const bf16x8*)(a0p + cb + 32);
        bf16x8 a10 = *(const bf16x8*)(a1p + cb), a11 = *(const bf16x8*)(a1p + cb + 32);
        bf16x8 a20 = *(const bf16x8*)(a2p + cb), a21 = *(const bf16x8*)(a2p + cb + 32);
        bf16x8 a30 = *(const bf16x8*)(a3p + cb), a31 = *(const bf16x8*)(a3p + cb + 32);
        const bf16_t* wl = &s_w[cur][kp * 4096 + lane * 8];
        bf16x8 w00 = *(const bf16x8*)(wl +    0), w01 = *(const bf16x8*)(wl +  512);
        bf16x8 w02 = *(const bf16x8*)(wl + 1024), w03 = *(const bf16x8*)(wl + 1536);
        bf16x8 w10 = *(const bf16x8*)(wl + 2048), w11 = *(const bf16x8*)(wl + 2560);
        bf16x8 w12 = *(const bf16x8*)(wl + 3072), w13 = *(const bf16x8*)(wl + 3584);
        MF16X(a00, a10, a20, a30, w00, w01, w02, w03);
        MF16X(a01, a11, a21, a31, w10, w11, w12, w13);
      }
      __syncthreads();
    }
  }

#pragma unroll
  for (int rt = 0; rt < 4; ++rt) {
#pragma unroll
    for (int reg = 0; reg < 4; ++reg) {
      int pt = pt0 + wv * 64 + rt * 16 + quad * 4 + reg;
#pragma unroll
      for (int cot = 0; cot < 4; ++cot) {
        int col = cot * 16 + m;
        float v = acc[rt][cot][reg];
        if (MODE == 0)      outh[(size_t)pt * hstride + hoff + col] = (bf16_t)v;
        else if (MODE == 1) outf[(size_t)pt * 64 + col] = v + bias[col];
        else                outf[(size_t)pt * 64 + col] += v;
      }
    }
  }
}

// T1/T0 stats (requires seg sorted over row index — original order)
__global__ void stats_kernel(const bf16_t* __restrict__ h, int stride, int off,
                             const int* __restrict__ seg,
                             float* __restrict__ sums, float* __restrict__ sumsq) {
  int tid = threadIdx.x;
  int co = tid & 63, pr = tid >> 6;
  int base = blockIdx.x * 1024;
  float s = 0.f, s2 = 0.f;
  int cur = seg[base];
  for (int i = pr; i < 1024; i += 4) {
    int pt = base + i;
    int sg = seg[pt];
    float v = (float)h[(size_t)pt * stride + off + co];
    if (sg != cur) {
      atomicAdd(&sums[cur * 64 + co], s);
      atomicAdd(&sumsq[cur * 64 + co], s2);
      s = 0.f; s2 = 0.f; cur = sg;
    }
    s += v; s2 += v * v;
  }
  atomicAdd(&sums[cur * 64 + co], s);
  atomicAdd(&sumsq[cur * 64 + co], s2);
}

// T2 stats: seg unsorted in tile order -> LDS bins
__global__ void stats_sorted(const bf16_t* __restrict__ h, int off,
                             const int* __restrict__ meta,
                             float* __restrict__ sums, float* __restrict__ sumsq) {
  __shared__ float bs[N_SEG * 64], bq[N_SEG * 64];
  int tid = threadIdx.x;
  for (int i = tid; i < N_SEG * 64; i += 256) { bs[i] = 0.f; bq[i] = 0.f; }
  __syncthreads();
  int co = tid & 63, pr = tid >> 6;
  int base = blockIdx.x * 1024;
  for (int i = pr; i < 1024; i += 4) {
    int pt = base + i;
    int sg = meta[pt] >> 20;
    float v = (float)h[(size_t)pt * 256 + off + co];
    atomicAdd(&bs[sg * 64 + co], v);
    atomicAdd(&bq[sg * 64 + co], v * v);
  }
  __syncthreads();
  for (int i = tid; i < N_SEG * 64; i += 256) {
    if (bs[i] != 0.f) atomicAdd(&sums[i], bs[i]);
    if (bq[i] != 0.f) atomicAdd(&sumsq[i], bq[i]);
  }
}

__global__ void params_kernel(const int* __restrict__ cnt, const float* __restrict__ sums,
                              const float* __restrict__ sumsq,
                              float* __restrict__ pA, float* __restrict__ pB) {
  int t = blockIdx.x * 256 + threadIdx.x;
  if (t < 1024) {
    int sgi = t >> 6;
    float c = (float)cnt[sgi];
    float a = 0.f, b = 0.f;
    if (c > 0.f) {
      float mean = sums[t] / c;
      float var = sumsq[t] / c - mean * mean;
      float inv = rsqrtf(var + EPS_V);
      a = inv; b = -mean * inv;
    }
    pA[t] = a; pB[t] = b;
  }
}

__global__ void norm_kernel(bf16_t* __restrict__ h, int stride, int off,
                            const int* __restrict__ seg,
                            const float* __restrict__ pA, const float* __restrict__ pB) {
  int i = blockIdx.x * 256 + threadIdx.x;   // N*16
  int pt = i >> 4;
  int cg = (i & 15) * 4;
  int sg = seg[pt];
  bf16_t* p = h + (size_t)pt * stride + off + cg;
  union { bf16_t hh[4]; uint2 u; } v;
  v.u = *(uint2*)p;
#pragma unroll
  for (int j = 0; j < 4; ++j) {
    float f = (float)v.hh[j] * pA[sg * 64 + cg + j] + pB[sg * 64 + cg + j];
    v.hh[j] = (bf16_t)fmaxf(f, 0.f);
  }
  *(uint2*)p = v.u;
}

__global__ void norm_sorted(bf16_t* __restrict__ h, int off,
                            const int* __restrict__ meta,
                            const float* __restrict__ pA, const float* __restrict__ pB) {
  int i = blockIdx.x * 256 + threadIdx.x;   // N*16
  int pt = i >> 4;
  int cg = (i & 15) * 4;
  int sg = meta[pt] >> 20;
  bf16_t* p = h + (size_t)pt * 256 + off + cg;
  union { bf16_t hh[4]; uint2 u; } v;
  v.u = *(uint2*)p;
#pragma unroll
  for (int j = 0; j < 4; ++j) {
    float f = (float)v.hh[j] * pA[sg * 64 + cg + j] + pB[sg * 64 + cg + j];
    v.hh[j] = (bf16_t)fmaxf(f, 0.f);
  }
  *(uint2*)p = v.u;
}

extern "C" void kernel_launch(void* const* d_in, const int* in_sizes, int n_in,
                              void* d_out, int out_size, void* d_ws, size_t ws_size,
                              hipStream_t stream) {
  const float* feats   = (const float*)d_in[0];
  const int*   indices = (const int*)d_in[1];
  const int*   seg     = (const int*)d_in[2];
  const float* w1 = (const float*)d_in[3];
  const float* w2 = (const float*)d_in[5];
  const float* w3 = (const float*)d_in[7];
  const float* wf = (const float*)d_in[9];
  const float* bf_ = (const float*)d_in[10];
  float* out = (float*)d_out;

  char* ws = (char*)d_ws;
  const bool t2 = (ws_size >= 141200000ull);
  const bool fused = t2 || (ws_size >= 139000000ull);

  int* idx_map = (int*)(ws + 0);
  hipMemsetAsync(idx_map, 0xFF, 4194304, stream);

  if (fused) {
    bf16_t* cat   = (bf16_t*)(ws + 4194304);
    bf16_t* wfrag = (bf16_t*)(ws + 138412544);
    float*  stats = (float*)(ws + 138928640);
    int* cnt  = (int*)stats;
    int* ymin = (int*)(stats + 16);
    int* ymax = (int*)(stats + 32);
    int* xmin = (int*)(stats + 48);
    int* xmax = (int*)(stats + 64);
    int* dseg = (int*)(stats + 80);
    float* sums  = stats + 128;
    float* sumsq = stats + 3200;
    float* pA    = stats + 6272;
    float* pB    = stats + 9344;
    int* hist   = t2 ? (int*)(ws + 138978304) : nullptr;
    int* cursor = t2 ? (int*)(ws + 138994688) : nullptr;
    int* ord    = t2 ? (int*)(ws + 139011072) : nullptr;
    int* meta   = t2 ? (int*)(ws + 140059648) : nullptr;

    hipMemsetAsync(cat + (size_t)N_PTS * 256, 0, 512, stream);   // sentinel row
    init_kernel<<<1, 256, 0, stream>>>(cnt, ymin, ymax, xmin, xmax, sums, sumsq, hist);
    scatter_kernel<<<N_PTS / 256, 256, 0, stream>>>(indices, seg, idx_map, cnt, ymin, ymax, xmin, xmax, hist);
    dilation_kernel<<<1, 64, 0, stream>>>(ymin, ymax, xmin, xmax, cnt, dseg);
    if (t2) {
      scan_kernel<<<1, 256, 0, stream>>>(hist, cursor);
      rank_kernel<<<N_PTS / 256, 256, 0, stream>>>(indices, seg, cursor, ord, meta, idx_map);
    }
    convert_kernel<<<16384, 256, 0, stream>>>((const float4*)feats, cat, 256, ord);
    repack_kernel<<<1008, 256, 0, stream>>>(w1, w2, w3, wf, wfrag);

    if (t2) {
      for (int r = 0; r < 3; ++r) {
        conv_sorted<2, 0><<<1024, 256, 0, stream>>>(cat, wfrag + (size_t)r * 36864, 4096,
                                                    meta, idx_map, dseg + r * 16, nullptr,
                                                    nullptr, cat, (r + 1) * 64, nullptr);
        stats_sorted<<<256, 256, 0, stream>>>(cat, (r + 1) * 64, meta,
                                              sums + r * 1024, sumsq + r * 1024);
        params_kernel<<<4, 256, 0, stream>>>(cnt, sums + r * 1024, sumsq + r * 1024,
                                             pA + r * 1024, pB + r * 1024);
        norm_sorted<<<16384, 256, 0, stream>>>(cat, (r + 1) * 64, meta,
                                               pA + r * 1024, pB + r * 1024);
      }
      conv_sorted<8, 1><<<1024, 256, 0, stream>>>(cat, wfrag + 110592, 16384,
                                                  meta, idx_map, nullptr, ord,
                                                  out, nullptr, 0, bf_);
    } else {
      for (int r = 0; r < 3; ++r) {
        conv_mfma<2, 0><<<1024, 256, 0, stream>>>(cat, 256, wfrag + (size_t)r * 36864, 4096,
                                                  indices, seg, idx_map, dseg + r * 16,
                                                  nullptr, cat, 256, (r + 1) * 64, nullptr);
        stats_kernel<<<256, 256, 0, stream>>>(cat, 256, (r + 1) * 64, seg,
                                              sums + r * 1024, sumsq + r * 1024);
        params_kernel<<<4, 256, 0, stream>>>(cnt, sums + r * 1024, sumsq + r * 1024,
                                             pA + r * 1024, pB + r * 1024);
        norm_kernel<<<16384, 256, 0, stream>>>(cat, 256, (r + 1) * 64, seg,
                                               pA + r * 1024, pB + r * 1024);
      }
      conv_mfma<8, 1><<<1024, 256, 0, stream>>>(cat, 256, wfrag + 110592, 16384,
                                                indices, seg, idx_map, nullptr,
                                                out, nullptr, 0, 0, bf_);
    }
  } else {
    bf16_t* feats_bf = (bf16_t*)(ws + 4194304);
    bf16_t* h_bf     = (bf16_t*)(ws + 37748864);
    bf16_t* wfrag    = (bf16_t*)(ws + 71303424);
    float*  stats    = (float*)(ws + 71819520);
    int* cnt  = (int*)stats;
    int* ymin = (int*)(stats + 16);
    int* ymax = (int*)(stats + 32);
    int* xmin = (int*)(stats + 48);
    int* xmax = (int*)(stats + 64);
    int* dseg = (int*)(stats + 80);
    float* sums  = stats + 128;
    float* sumsq = stats + 3200;
    float* pA    = stats + 6272;
    float* pB    = stats + 9344;

    hipMemsetAsync(feats_bf + (size_t)N_PTS * 64, 0, 128, stream);
    hipMemsetAsync(h_bf + (size_t)N_PTS * 64, 0, 128, stream);
    init_kernel<<<1, 256, 0, stream>>>(cnt, ymin, ymax, xmin, xmax, sums, sumsq, nullptr);
    scatter_kernel<<<N_PTS / 256, 256, 0, stream>>>(indices, seg, idx_map, cnt, ymin, ymax, xmin, xmax, nullptr);
    dilation_kernel<<<1, 64, 0, stream>>>(ymin, ymax, xmin, xmax, cnt, dseg);
    convert_kernel<<<16384, 256, 0, stream>>>((const float4*)feats, feats_bf, 64, nullptr);
    repack_kernel<<<1008, 256, 0, stream>>>(w1, w2, w3, wf, wfrag);

    conv_mfma<2, 1><<<1024, 256, 0, stream>>>(feats_bf, 64, wfrag + 110592, 16384,
                                              indices, seg, idx_map, nullptr,
                                              out, nullptr, 0, 0, bf_);
    for (int r = 0; r < 3; ++r) {
      conv_mfma<2, 0><<<1024, 256, 0, stream>>>(feats_bf, 64, wfrag + (size_t)r * 36864, 4096,
                                                indices, seg, idx_map, dseg + r * 16,
                                                nullptr, h_bf, 64, 0, nullptr);
      stats_kernel<<<256, 256, 0, stream>>>(h_bf, 64, 0, seg, sums + r * 1024, sumsq + r * 1024);
      params_kernel<<<4, 256, 0, stream>>>(cnt, sums + r * 1024, sumsq + r * 1024,
                                           pA + r * 1024, pB + r * 1024);
      norm_kernel<<<16384, 256, 0, stream>>>(h_bf, 64, 0, seg, pA + r * 1024, pB + r * 1024);
      conv_mfma<2, 2><<<1024, 256, 0, stream>>>(h_bf, 64, wfrag + 110592 + (size_t)(r + 1) * 4096, 16384,
                                                indices, seg, idx_map, nullptr,
                                                out, nullptr, 0, 0, nullptr);
    }
  }
}

// Round 5
// 1018.922 us; speedup vs baseline: 1.0004x; 1.0004x over previous
//
#include <hip/hip_runtime.h>
#include <hip/hip_bf16.h>
#include <stdint.h>

#define N_PTS   262144
#define H_DIM   512
#define W_DIM   512
#define N_SEG   16
#define EPS_V   1e-5f

typedef __bf16 bf16_t;
typedef __bf16 bf16x8 __attribute__((ext_vector_type(8)));
typedef float  f32x4  __attribute__((ext_vector_type(4)));

// async global->LDS, 16B per lane. LDS dest must be wave-uniform base + lane*16.
__device__ __forceinline__ void gl_lds16(const bf16_t* g, bf16_t* l) {
  __builtin_amdgcn_global_load_lds(
      (const __attribute__((address_space(1))) unsigned int*)g,
      (__attribute__((address_space(3))) unsigned int*)l, 16, 0, 0);
}

// ------------- workspace layouts -------------
// T2 SORTED (ws >= 141.2 MB):
//   idx_map int[4*512*512]  @ 0          (seg<<18)|sorted_pos, -1 empty
//   cat     bf16[(N+1)*256] @ 4194304    SORTED rows: cat[pos] = point ord[pos]
//   wfrag   bf16[258048]    @ 138412544
//   stats   float[12416]    @ 138928640
//   hist    int[4096]       @ 138978304
//   cursor  int[4096]       @ 138994688
//   ord     int[N]          @ 139011072  sorted pos -> original idx
//   meta    int[N]          @ 140059648  (seg<<20)|(b<<18)|(y<<9)|x per sorted pos
// T1 FUSED (ws >= 139 MB): unsorted fallback
// T0 FALLBACK: 64-ch buffers at 72 MB.
// stats block (floats): cnt[16]@0 ymin@16 ymax@32 xmin@48 xmax@64 dseg[48]@80
//   sums[3*1024]@128 sumsq[3*1024]@3200 pA[3*1024]@6272 pB[3*1024]@9344

__global__ void init_kernel(int* cnt, int* ymin, int* ymax, int* xmin, int* xmax,
                            float* sums, float* sumsq, int* hist) {
  int t = threadIdx.x;
  if (t < N_SEG) {
    cnt[t] = 0;
    ymin[t] = 0x7fffffff; ymax[t] = (int)0x80000000;
    xmin[t] = 0x7fffffff; xmax[t] = (int)0x80000000;
  }
  for (int i = t; i < 3 * 1024; i += 256) { sums[i] = 0.f; sumsq[i] = 0.f; }
  if (hist) for (int i = t; i < 4096; i += 256) hist[i] = 0;
}

__global__ void scatter_kernel(const int* __restrict__ indices,
                               const int* __restrict__ seg,
                               int* __restrict__ idx_map,
                               int* __restrict__ cnt,
                               int* __restrict__ ymin, int* __restrict__ ymax,
                               int* __restrict__ xmin, int* __restrict__ xmax,
                               int* __restrict__ hist) {
  __shared__ int lc[N_SEG], ly0[N_SEG], ly1[N_SEG], lx0[N_SEG], lx1[N_SEG];
  int tid = threadIdx.x;
  if (tid < N_SEG) {
    lc[tid] = 0;
    ly0[tid] = 0x7fffffff; ly1[tid] = (int)0x80000000;
    lx0[tid] = 0x7fffffff; lx1[tid] = (int)0x80000000;
  }
  __syncthreads();
  int i = blockIdx.x * 256 + tid;
  int b = indices[i * 3], y = indices[i * 3 + 1], x = indices[i * 3 + 2];
  int s = seg[i];
  idx_map[(b * H_DIM + y) * W_DIM + x] = (s << 18) | i;   // T1 packing; T2 overwrites in rank
  atomicAdd(&lc[s], 1);
  atomicMin(&ly0[s], y); atomicMax(&ly1[s], y);
  atomicMin(&lx0[s], x); atomicMax(&lx1[s], x);
  if (hist) {
    int key = (b << 10) | ((y >> 4) << 5) | (x >> 4);     // 4096 spatial tiles
    atomicAdd(&hist[key], 1);
  }
  __syncthreads();
  if (tid < N_SEG && lc[tid] > 0) {
    atomicAdd(&cnt[tid], lc[tid]);
    atomicMin(&ymin[tid], ly0[tid]); atomicMax(&ymax[tid], ly1[tid]);
    atomicMin(&xmin[tid], lx0[tid]); atomicMax(&xmax[tid], lx1[tid]);
  }
}

// exclusive prefix sum of hist[4096] -> cursor[4096]
__global__ void scan_kernel(const int* __restrict__ hist, int* __restrict__ cursor) {
  __shared__ int s[256];
  int t = threadIdx.x;
  int base = t * 16;
  int loc[16];
  int acc = 0;
#pragma unroll
  for (int j = 0; j < 16; ++j) { loc[j] = acc; acc += hist[base + j]; }
  s[t] = acc;
  __syncthreads();
  for (int o = 1; o < 256; o <<= 1) {
    int v = (t >= o) ? s[t - o] : 0;
    __syncthreads();
    s[t] += v;
    __syncthreads();
  }
  int pre = (t == 0) ? 0 : s[t - 1];
#pragma unroll
  for (int j = 0; j < 16; ++j) cursor[base + j] = pre + loc[j];
}

// T2 rank: assigns sorted pos; writes ord, packed meta, and pos-packed idx_map
__global__ void rank_kernel(const int* __restrict__ indices,
                            const int* __restrict__ seg,
                            int* __restrict__ cursor, int* __restrict__ ord,
                            int* __restrict__ meta, int* __restrict__ idx_map) {
  int i = blockIdx.x * 256 + threadIdx.x;
  int b = indices[i * 3], y = indices[i * 3 + 1], x = indices[i * 3 + 2];
  int key = (b << 10) | ((y >> 4) << 5) | (x >> 4);
  int pos = atomicAdd(&cursor[key], 1);
  int s = seg[i];
  ord[pos] = i;
  meta[pos] = (s << 20) | (b << 18) | (y << 9) | x;
  idx_map[(b * H_DIM + y) * W_DIM + x] = (s << 18) | pos;
}

__global__ void dilation_kernel(const int* ymin, const int* ymax,
                                const int* xmin, const int* xmax,
                                const int* cnt, int* dseg) {
  int t = threadIdx.x;
  if (t < 48) {
    int r = t >> 4, s = t & 15;
    int rate = (r == 0) ? 1 : (r == 1) ? 3 : 5;
    int d = 1;
    if (cnt[s] > 0) {
      float hr = (float)(ymax[s] - ymin[s]) * (1.0f / H_DIM);
      float wr = (float)(xmax[s] - xmin[s]) * (1.0f / W_DIM);
      d = (int)ceilf(fmaxf(hr, wr) * (float)rate);
      if (d < 1) d = 1;
    }
    dseg[t] = d;
  }
}

// features fp32 -> bf16 rows; dst row pt <- src row (ord? ord[pt] : pt)
__global__ void convert_kernel(const float4* __restrict__ in, bf16_t* __restrict__ dst,
                               int stride, const int* __restrict__ ord) {
  int i = blockIdx.x * 256 + threadIdx.x;   // N*16
  int pt = i >> 4, g = i & 15;
  int sp = ord ? ord[pt] : pt;
  float4 v = in[(size_t)sp * 16 + g];
  union { bf16_t h[4]; uint2 u; } o;
  o.h[0] = (bf16_t)v.x; o.h[1] = (bf16_t)v.y;
  o.h[2] = (bf16_t)v.z; o.h[3] = (bf16_t)v.w;
  *(uint2*)(dst + (size_t)pt * stride + g * 4) = o.u;
}

// wfrag: [0,110592): branch r in {0,1,2} at r*36864, layout [k][kk2][cot][lane][j]
//        [110592,258048): fused final, layout [k][kk8][cot][lane][j], kk8=0..7
__global__ void repack_kernel(const float* __restrict__ w1, const float* __restrict__ w2,
                              const float* __restrict__ w3, const float* __restrict__ wf,
                              bf16_t* __restrict__ wfrag) {
  int e = blockIdx.x * 256 + threadIdx.x;   // < 258048
  if (e < 110592) {
    int s = e / 36864, rem = e % 36864;
    int k = rem >> 12, r2 = rem & 4095;
    int kk = r2 >> 11, r3 = r2 & 2047;
    int cot = r3 >> 9, r4 = r3 & 511;
    int lane = r4 >> 3, j = r4 & 7;
    int c  = kk * 32 + (lane >> 4) * 8 + j;
    int co = cot * 16 + (lane & 15);
    const float* w = (s == 0) ? w1 : (s == 1) ? w2 : w3;
    wfrag[e] = (bf16_t)w[k * 4096 + c * 64 + co];
  } else {
    int ef = e - 110592;
    int k = ef >> 14, r2 = ef & 16383;
    int kk8 = r2 >> 11, r3 = r2 & 2047;
    int cot = r3 >> 9, r4 = r3 & 511;
    int lane = r4 >> 3, j = r4 & 7;
    int c  = kk8 * 32 + (lane >> 4) * 8 + j;   // 0..255
    int co = cot * 16 + (lane & 15);
    wfrag[e] = (bf16_t)wf[k * 16384 + c * 64 + co];
  }
}

#define MF(ar, wr, i, j) \
  acc[i][j] = __builtin_amdgcn_mfma_f32_16x16x32_bf16(ar, wr, acc[i][j], 0, 0, 0)

// ============ T2 sorted conv ============
// cat rows are tile-sorted: a block's 256 points are rows [pt0, pt0+256) --
// contiguous. Block stages its OWN rows into LDS (coalesced global_load_lds,
// 16B-piece XOR swizzle via pre-swizzled global source); taps read LDS for
// in-block neighbors with masked global fallback. Outputs bounce through LDS
// to coalesced stores. Attacks per-CU vector-memory address throughput.
template <int KK, int MODE>
__launch_bounds__(256, 2)
__global__ void conv_sorted(const bf16_t* __restrict__ A,
                            const bf16_t* __restrict__ wfrag, int wkstride,
                            const int* __restrict__ meta,
                            const int* __restrict__ idx_map,
                            const int* __restrict__ dseg,
                            const int* __restrict__ ord,
                            float* __restrict__ outf,
                            bf16_t* __restrict__ outh, int hoff,
                            const float* __restrict__ bias) {
  __shared__ __align__(16) bf16_t s_a[256 * 64];   // 32 KB
  __shared__ __align__(16) bf16_t s_w[2][4096];    // 16 KB dbuf
  __shared__ int s_nbr[9 * 256];
  __shared__ int s_pt[256];
  const int tid = threadIdx.x;
  int bid = blockIdx.x;
  bid = (bid & 7) * ((int)gridDim.x >> 3) + (bid >> 3);   // XCD swizzle (1024%8==0)
  const int pt0 = bid * 256;

  // ---- setup: coalesced meta, spatially-local idx_map gathers ----
  {
    int mt = meta[pt0 + tid];
    if (MODE == 1) s_pt[tid] = ord[pt0 + tid];
    int sg = mt >> 20;
    int b = (mt >> 18) & 3, y = (mt >> 9) & 511, x = mt & 511;
    int d = (MODE == 0) ? dseg[sg] : 1;
#pragma unroll
    for (int k = 0; k < 9; ++k) {
      int ky = (k / 3) - 1, kx = (k % 3) - 1;
      int ny = y + ky * d, nx = x + kx * d;
      int e = N_PTS;                           // sentinel zero row
      if (ny >= 0 && ny < H_DIM && nx >= 0 && nx < W_DIM) {
        int v = idx_map[(b * H_DIM + ny) * W_DIM + nx];
        if (v >= 0) {
          int pos2 = v & 0x3FFFF;
          if (MODE == 0) { if ((v >> 18) == sg) e = pos2; }
          else e = pos2;
        }
      }
      unsigned lo = (unsigned)(e - pt0);
      s_nbr[k * 256 + tid] = (lo < 256u) ? -(int)(lo + 1) : e;   // neg = local slot
    }
  }

  const int lane = tid & 63;
  const int wv = tid >> 6;
  const int m = lane & 15;
  const int quad = lane >> 4;
  const int rb = wv * 64 + m;

  float b4[4];
  if (MODE == 1) {
#pragma unroll
    for (int cot = 0; cot < 4; ++cot) b4[cot] = bias[cot * 16 + m];
  }

  // stage own rows, quarter q (64ch = 8 x 16B pieces per row), piece-XOR-swizzled
  auto stageA = [&](int q) {
#pragma unroll
    for (int s = 0; s < 8; ++s) {
      int ch = s * 256 + tid;
      int r = ch >> 3, p = ch & 7;
      int ps = p ^ (r & 7);
      gl_lds16(A + (size_t)(pt0 + r) * 256 + q * 64 + ps * 8, &s_a[ch * 8]);
    }
  };
  auto stageW = [&](int k, int q, int buf) {
    const bf16_t* src = wfrag + (size_t)k * wkstride + q * 4096;
#pragma unroll
    for (int s = 0; s < 2; ++s) {
      int off = s * 2048 + tid * 8;
      gl_lds16(src + off, &s_w[buf][off]);
    }
  };

  f32x4 acc[4][4];
#pragma unroll
  for (int rt = 0; rt < 4; ++rt)
#pragma unroll
    for (int c = 0; c < 4; ++c) {
      acc[rt][c][0] = 0.f; acc[rt][c][1] = 0.f;
      acc[rt][c][2] = 0.f; acc[rt][c][3] = 0.f;
    }

  constexpr int NQ = (KK == 8) ? 4 : 1;
  for (int q = 0; q < NQ; ++q) {
    __syncthreads();                   // prev-quarter readers done / setup visible
    stageA(q);
    stageW(0, q, 0);
    __syncthreads();                   // drains vmcnt: s_a + s_w[0] ready
    int buf = 0;
    for (int k = 0; k < 9; ++k) {
      if (k < 8) stageW(k + 1, q, buf ^ 1);
      const int* sn = s_nbr + k * 256;
#pragma unroll
      for (int rt = 0; rt < 4; ++rt) {
        int e = sn[rb + rt * 16];
        bool loc = e < 0;
        int slot = loc ? (-e - 1) : 0;
        int grow = loc ? N_PTS : e;
        const bf16_t* gp = A + (size_t)grow * 256 + q * 64 + quad * 8;
        bf16x8 g0 = *(const bf16x8*)(gp);
        bf16x8 g1 = *(const bf16x8*)(gp + 32);
        int sw = slot & 7;
        bf16x8 l0 = *(const bf16x8*)&s_a[slot * 64 + ((quad ^ sw) << 3)];
        bf16x8 l1 = *(const bf16x8*)&s_a[slot * 64 + (((4 + quad) ^ sw) << 3)];
        bf16x8 a0 = loc ? l0 : g0;
        bf16x8 a1 = loc ? l1 : g1;
        const bf16_t* wl = &s_w[buf][lane * 8];
        MF(a0, *(const bf16x8*)(wl +    0), rt, 0);
        MF(a0, *(const bf16x8*)(wl +  512), rt, 1);
        MF(a0, *(const bf16x8*)(wl + 1024), rt, 2);
        MF(a0, *(const bf16x8*)(wl + 1536), rt, 3);
        MF(a1, *(const bf16x8*)(wl + 2048), rt, 0);
        MF(a1, *(const bf16x8*)(wl + 2560), rt, 1);
        MF(a1, *(const bf16x8*)(wl + 3072), rt, 2);
        MF(a1, *(const bf16x8*)(wl + 3584), rt, 3);
      }
      __syncthreads();                 // all done with s_w[buf]; next stage landed
      buf ^= 1;
    }
  }

  // ---- epilogue via LDS bounce -> coalesced stores ----
  if (MODE == 0) {
#pragma unroll
    for (int rt = 0; rt < 4; ++rt)
#pragma unroll
      for (int reg = 0; reg < 4; ++reg) {
        int row = wv * 64 + rt * 16 + quad * 4 + reg;
#pragma unroll
        for (int cot = 0; cot < 4; ++cot) {
          int col = cot * 16 + m;
          int p = col >> 3;
          s_a[row * 64 + (((p ^ (row & 7)) << 3) | (col & 7))] = (bf16_t)acc[rt][cot][reg];
        }
      }
    __syncthreads();
#pragma unroll
    for (int s = 0; s < 8; ++s) {
      int g = s * 256 + tid;
      int r = g >> 3, p = g & 7;
      uint4 v = *(const uint4*)&s_a[r * 64 + ((p ^ (r & 7)) << 3)];
      *(uint4*)(outh + (size_t)(pt0 + r) * 256 + hoff + p * 8) = v;
    }
  } else {
    float* s_af = (float*)s_a;         // 256 x 32 f32 per half
#pragma unroll
    for (int hh = 0; hh < 2; ++hh) {
      if (hh) __syncthreads();
#pragma unroll
      for (int rt = 0; rt < 4; ++rt)
#pragma unroll
        for (int reg = 0; reg < 4; ++reg) {
          int row = wv * 64 + rt * 16 + quad * 4 + reg;
#pragma unroll
          for (int c2 = 0; c2 < 2; ++c2) {
            int cot = hh * 2 + c2;
            int col32 = c2 * 16 + m;
            int p = col32 >> 2;
            s_af[row * 32 + (((p ^ (row & 7)) << 2) | (col32 & 3))] =
                acc[rt][cot][reg] + b4[cot];
          }
        }
      __syncthreads();
#pragma unroll
      for (int s = 0; s < 8; ++s) {
        int g = s * 256 + tid;
        int r = g >> 3, p = g & 7;
        float4 v = *(const float4*)&s_af[r * 32 + ((p ^ (r & 7)) << 2)];
        *(float4*)(outf + (size_t)s_pt[r] * 64 + hh * 32 + p * 4) = v;
      }
    }
  }
}

// ============ T1/T0 conv (round-3 version, unsorted-safe) ============
template <int KK, int MODE>
__launch_bounds__(256, 3)
__global__ void conv_mfma(const bf16_t* __restrict__ A, int astride,
                          const bf16_t* __restrict__ wfrag, int wkstride,
                          const int* __restrict__ indices,
                          const int* __restrict__ seg,
                          const int* __restrict__ idx_map,
                          const int* __restrict__ dseg,
                          float* __restrict__ outf,
                          bf16_t* __restrict__ outh, int hstride, int hoff,
                          const float* __restrict__ bias) {
  constexpr int WELEM = (KK == 8) ? 8192 : 4096;
  constexpr int SWEEPS = (KK == 8) ? 4 : 2;
  __shared__ int s_nbr[9 * 256];
  __shared__ __align__(16) bf16_t s_w[2][WELEM];
  const int tid = threadIdx.x;
  const int pt0 = blockIdx.x * 256;

  {
    int pt = pt0 + tid;
    int b = indices[pt * 3], y = indices[pt * 3 + 1], x = indices[pt * 3 + 2];
    int sg = 0, d = 1;
    if (MODE == 0) { sg = seg[pt]; d = dseg[sg]; }
#pragma unroll
    for (int k = 0; k < 9; ++k) {
      int ky = (k / 3) - 1, kx = (k % 3) - 1;
      int ny = y + ky * d, nx = x + kx * d;
      int nbr = N_PTS;
      if (ny >= 0 && ny < H_DIM && nx >= 0 && nx < W_DIM) {
        int v = idx_map[(b * H_DIM + ny) * W_DIM + nx];
        if (v >= 0) {
          if (MODE == 0) nbr = ((v >> 18) == sg) ? (v & 0x3FFFF) : N_PTS;
          else           nbr = v & 0x3FFFF;
        }
      }
      s_nbr[k * 256 + tid] = nbr;
    }
  }

  auto stage = [&](int ph, int buf) {
    const bf16_t* src;
    if constexpr (KK == 8) src = wfrag + (size_t)(ph >> 1) * wkstride + (ph & 1) * 8192;
    else                   src = wfrag + (size_t)ph * wkstride;
#pragma unroll
    for (int s = 0; s < SWEEPS; ++s) {
      int off = s * 2048 + tid * 8;
      gl_lds16(src + off, &s_w[buf][off]);
    }
  };

  stage(0, 0);
  __syncthreads();

  const int lane = tid & 63;
  const int wv = tid >> 6;
  const int m = lane & 15;
  const int quad = lane >> 4;
  const int rbase = wv * 64 + m;

  f32x4 acc[4][4];
#pragma unroll
  for (int rt = 0; rt < 4; ++rt)
#pragma unroll
    for (int c = 0; c < 4; ++c) {
      acc[rt][c][0] = 0.f; acc[rt][c][1] = 0.f;
      acc[rt][c][2] = 0.f; acc[rt][c][3] = 0.f;
    }

#define MF16X(A0, A1, A2, A3, W0, W1, W2, W3) \
  MF(A0, W0, 0, 0); MF(A0, W1, 0, 1); MF(A0, W2, 0, 2); MF(A0, W3, 0, 3); \
  MF(A1, W0, 1, 0); MF(A1, W1, 1, 1); MF(A1, W2, 1, 2); MF(A1, W3, 1, 3); \
  MF(A2, W0, 2, 0); MF(A2, W1, 2, 1); MF(A2, W2, 2, 2); MF(A2, W3, 2, 3); \
  MF(A3, W0, 3, 0); MF(A3, W1, 3, 1); MF(A3, W2, 3, 2); MF(A3, W3, 3, 3)

  if constexpr (KK == 2) {
    for (int k = 0; k < 9; ++k) {
      const int cur = k & 1;
      if (k < 8) stage(k + 1, cur ^ 1);
      const int* sn = s_nbr + k * 256 + rbase;
      const bf16_t* a0p = A + (size_t)sn[0]  * astride + quad * 8;
      const bf16_t* a1p = A + (size_t)sn[16] * astride + quad * 8;
      const bf16_t* a2p = A + (size_t)sn[32] * astride + quad * 8;
      const bf16_t* a3p = A + (size_t)sn[48] * astride + quad * 8;
      bf16x8 a00 = *(const bf16x8*)(a0p), a01 = *(const bf16x8*)(a0p + 32);
      bf16x8 a10 = *(const bf16x8*)(a1p), a11 = *(const bf16x8*)(a1p + 32);
      bf16x8 a20 = *(const bf16x8*)(a2p), a21 = *(const bf16x8*)(a2p + 32);
      bf16x8 a30 = *(const bf16x8*)(a3p), a31 = *(const bf16x8*)(a3p + 32);
      const bf16_t* wl = &s_w[cur][lane * 8];
      bf16x8 w00 = *(const bf16x8*)(wl +    0), w01 = *(const bf16x8*)(wl +  512);
      bf16x8 w02 = *(const bf16x8*)(wl + 1024), w03 = *(const bf16x8*)(wl + 1536);
      bf16x8 w10 = *(const bf16x8*)(wl + 2048), w11 = *(const bf16x8*)(wl + 2560);
      bf16x8 w12 = *(const bf16x8*)(wl + 3072), w13 = *(const bf16x8*)(wl + 3584);
      MF16X(a00, a10, a20, a30, w00, w01, w02, w03);
      MF16X(a01, a11, a21, a31, w10, w11, w12, w13);
      __syncthreads();
    }
  } else {
    for (int h = 0; h < 18; ++h) {
      const int cur = h & 1;
      if (h < 17) stage(h + 1, cur ^ 1);
      const int k = h >> 1;
      const int colb = (h & 1) * 128;
      const int* sn = s_nbr + k * 256 + rbase;
      const bf16_t* a0p = A + (size_t)sn[0]  * astride + quad * 8 + colb;
      const bf16_t* a1p = A + (size_t)sn[16] * astride + quad * 8 + colb;
      const bf16_t* a2p = A + (size_t)sn[32] * astride + quad * 8 + colb;
      const bf16_t* a3p = A + (size_t)sn[48] * astride + quad * 8 + colb;
#pragma unroll
      for (int kp = 0; kp < 2; ++kp) {
        const int cb = kp * 64;
        bf16x8 a00 = *(const bf16x8*)(a0p + cb), a01 = *(const bf16x8*)(a0p + cb + 32);
        bf16x8 a10 = *(const bf16x8*)(a1p + cb), a11 = *(const bf16x8*)(a1p + cb + 32);
        bf16x8 a20 = *(const bf16x8*)(a2p + cb), a21 = *(const bf16x8*)(a2p + cb + 32);
        bf16x8 a30 = *(const bf16x8*)(a3p + cb), a31 = *(const bf16x8*)(a3p + cb + 32);
        const bf16_t* wl = &s_w[cur][kp * 4096 + lane * 8];
        bf16x8 w00 = *(const bf16x8*)(wl +    0), w01 = *(const bf16x8*)(wl +  512);
        bf16x8 w02 = *(const bf16x8*)(wl + 1024), w03 = *(const bf16x8*)(wl + 1536);
        bf16x8 w10 = *(const bf16x8*)(wl + 2048), w11 = *(const bf16x8*)(wl + 2560);
        bf16x8 w12 = *(const bf16x8*)(wl + 3072), w13 = *(const bf16x8*)(wl + 3584);
        MF16X(a00, a10, a20, a30, w00, w01, w02, w03);
        MF16X(a01, a11, a21, a31, w10, w11, w12, w13);
      }
      __syncthreads();
    }
  }

#pragma unroll
  for (int rt = 0; rt < 4; ++rt) {
#pragma unroll
    for (int reg = 0; reg < 4; ++reg) {
      int pt = pt0 + wv * 64 + rt * 16 + quad * 4 + reg;
#pragma unroll
      for (int cot = 0; cot < 4; ++cot) {
        int col = cot * 16 + m;
        float v = acc[rt][cot][reg];
        if (MODE == 0)      outh[(size_t)pt * hstride + hoff + col] = (bf16_t)v;
        else if (MODE == 1) outf[(size_t)pt * 64 + col] = v + bias[col];
        else                outf[(size_t)pt * 64 + col] += v;
      }
    }
  }
}

// T1/T0 stats (requires seg sorted over row index — original order)
__global__ void stats_kernel(const bf16_t* __restrict__ h, int stride, int off,
                             const int* __restrict__ seg,
                             float* __restrict__ sums, float* __restrict__ sumsq) {
  int tid = threadIdx.x;
  int co = tid & 63, pr = tid >> 6;
  int base = blockIdx.x * 1024;
  float s = 0.f, s2 = 0.f;
  int cur = seg[base];
  for (int i = pr; i < 1024; i += 4) {
    int pt = base + i;
    int sg = seg[pt];
    float v = (float)h[(size_t)pt * stride + off + co];
    if (sg != cur) {
      atomicAdd(&sums[cur * 64 + co], s);
      atomicAdd(&sumsq[cur * 64 + co], s2);
      s = 0.f; s2 = 0.f; cur = sg;
    }
    s += v; s2 += v * v;
  }
  atomicAdd(&sums[cur * 64 + co], s);
  atomicAdd(&sumsq[cur * 64 + co], s2);
}

// T2 stats, rebuilt (round-4 version was a latency chain: per-iteration global
// meta load gating LDS atomics + same-order global flush = 180us).
// Fixes: seg IDs preloaded to LDS once; uint2 (4ch) h loads, independent &
// unrollable; LDS float bins; per-block flush order rotated by blockIdx so
// concurrent global atomics never align on the same address.
__global__ void __launch_bounds__(512)
stats_sorted(const bf16_t* __restrict__ h, int off,
             const int* __restrict__ meta,
             float* __restrict__ sums, float* __restrict__ sumsq) {
  __shared__ float bs[1024], bq[1024];
  __shared__ unsigned char ssg[1024];
  int tid = threadIdx.x;
  int base = blockIdx.x * 1024;
  for (int i = tid; i < 1024; i += 512) {
    bs[i] = 0.f; bq[i] = 0.f;
    ssg[i] = (unsigned char)(meta[base + i] >> 20);
  }
  __syncthreads();
  // 1024 rows x 16 col-groups of 4ch = 16384 items / 512 thr = 32 iters
#pragma unroll 4
  for (int it = 0; it < 32; ++it) {
    int idx = it * 512 + tid;
    int row = idx >> 4, cg = (idx & 15) << 2;
    union { bf16_t hh[4]; uint2 u; } v;
    v.u = *(const uint2*)(h + (size_t)(base + row) * 256 + off + cg);
    int b0 = ssg[row] * 64 + cg;
#pragma unroll
    for (int j = 0; j < 4; ++j) {
      float f = (float)v.hh[j];
      atomicAdd(&bs[b0 + j], f);
      atomicAdd(&bq[b0 + j], f * f);
    }
  }
  __syncthreads();
  int rot = (blockIdx.x * 97) & 1023;          // spread hot addresses over time
  for (int i = tid; i < 1024; i += 512) {
    int j = (i + rot) & 1023;
    atomicAdd(&sums[j], bs[j]);
    atomicAdd(&sumsq[j], bq[j]);
  }
}

__global__ void params_kernel(const int* __restrict__ cnt, const float* __restrict__ sums,
                              const float* __restrict__ sumsq,
                              float* __restrict__ pA, float* __restrict__ pB) {
  int t = blockIdx.x * 256 + threadIdx.x;
  if (t < 1024) {
    int sgi = t >> 6;
    float c = (float)cnt[sgi];
    float a = 0.f, b = 0.f;
    if (c > 0.f) {
      float mean = sums[t] / c;
      float var = sumsq[t] / c - mean * mean;
      float inv = rsqrtf(var + EPS_V);
      a = inv; b = -mean * inv;
    }
    pA[t] = a; pB[t] = b;
  }
}

__global__ void norm_kernel(bf16_t* __restrict__ h, int stride, int off,
                            const int* __restrict__ seg,
                            const float* __restrict__ pA, const float* __restrict__ pB) {
  int i = blockIdx.x * 256 + threadIdx.x;   // N*16
  int pt = i >> 4;
  int cg = (i & 15) * 4;
  int sg = seg[pt];
  bf16_t* p = h + (size_t)pt * stride + off + cg;
  union { bf16_t hh[4]; uint2 u; } v;
  v.u = *(uint2*)p;
#pragma unroll
  for (int j = 0; j < 4; ++j) {
    float f = (float)v.hh[j] * pA[sg * 64 + cg + j] + pB[sg * 64 + cg + j];
    v.hh[j] = (bf16_t)fmaxf(f, 0.f);
  }
  *(uint2*)p = v.u;
}

// T2 norm: 8ch per thread, float4 param loads
__global__ void norm_sorted(bf16_t* __restrict__ h, int off,
                            const int* __restrict__ meta,
                            const float* __restrict__ pA, const float* __restrict__ pB) {
  int i = blockIdx.x * 256 + threadIdx.x;   // N*8
  int pt = i >> 3;
  int cg = (i & 7) * 8;
  int sg = meta[pt] >> 20;
  bf16_t* p = h + (size_t)pt * 256 + off + cg;
  union { bf16_t hh[8]; uint4 u; } v;
  v.u = *(uint4*)p;
  float4 a0 = *(const float4*)&pA[sg * 64 + cg];
  float4 a1 = *(const float4*)&pA[sg * 64 + cg + 4];
  float4 b0 = *(const float4*)&pB[sg * 64 + cg];
  float4 b1 = *(const float4*)&pB[sg * 64 + cg + 4];
  float av[8] = {a0.x, a0.y, a0.z, a0.w, a1.x, a1.y, a1.z, a1.w};
  float bv[8] = {b0.x, b0.y, b0.z, b0.w, b1.x, b1.y, b1.z, b1.w};
#pragma unroll
  for (int j = 0; j < 8; ++j) {
    float f = (float)v.hh[j] * av[j] + bv[j];
    v.hh[j] = (bf16_t)fmaxf(f, 0.f);
  }
  *(uint4*)p = v.u;
}

extern "C" void kernel_launch(void* const* d_in, const int* in_sizes, int n_in,
                              void* d_out, int out_size, void* d_ws, size_t ws_size,
                              hipStream_t stream) {
  const float* feats   = (const float*)d_in[0];
  const int*   indices = (const int*)d_in[1];
  const int*   seg     = (const int*)d_in[2];
  const float* w1 = (const float*)d_in[3];
  const float* w2 = (const float*)d_in[5];
  const float* w3 = (const float*)d_in[7];
  const float* wf = (const float*)d_in[9];
  const float* bf_ = (const float*)d_in[10];
  float* out = (float*)d_out;

  char* ws = (char*)d_ws;
  const bool t2 = (ws_size >= 141200000ull);
  const bool fused = t2 || (ws_size >= 139000000ull);

  int* idx_map = (int*)(ws + 0);
  hipMemsetAsync(idx_map, 0xFF, 4194304, stream);

  if (fused) {
    bf16_t* cat   = (bf16_t*)(ws + 4194304);
    bf16_t* wfrag = (bf16_t*)(ws + 138412544);
    float*  stats = (float*)(ws + 138928640);
    int* cnt  = (int*)stats;
    int* ymin = (int*)(stats + 16);
    int* ymax = (int*)(stats + 32);
    int* xmin = (int*)(stats + 48);
    int* xmax = (int*)(stats + 64);
    int* dseg = (int*)(stats + 80);
    float* sums  = stats + 128;
    float* sumsq = stats + 3200;
    float* pA    = stats + 6272;
    float* pB    = stats + 9344;
    int* hist   = t2 ? (int*)(ws + 138978304) : nullptr;
    int* cursor = t2 ? (int*)(ws + 138994688) : nullptr;
    int* ord    = t2 ? (int*)(ws + 139011072) : nullptr;
    int* meta   = t2 ? (int*)(ws + 140059648) : nullptr;

    hipMemsetAsync(cat + (size_t)N_PTS * 256, 0, 512, stream);   // sentinel row
    init_kernel<<<1, 256, 0, stream>>>(cnt, ymin, ymax, xmin, xmax, sums, sumsq, hist);
    scatter_kernel<<<N_PTS / 256, 256, 0, stream>>>(indices, seg, idx_map, cnt, ymin, ymax, xmin, xmax, hist);
    dilation_kernel<<<1, 64, 0, stream>>>(ymin, ymax, xmin, xmax, cnt, dseg);
    if (t2) {
      scan_kernel<<<1, 256, 0, stream>>>(hist, cursor);
      rank_kernel<<<N_PTS / 256, 256, 0, stream>>>(indices, seg, cursor, ord, meta, idx_map);
    }
    convert_kernel<<<16384, 256, 0, stream>>>((const float4*)feats, cat, 256, ord);
    repack_kernel<<<1008, 256, 0, stream>>>(w1, w2, w3, wf, wfrag);

    if (t2) {
      for (int r = 0; r < 3; ++r) {
        conv_sorted<2, 0><<<1024, 256, 0, stream>>>(cat, wfrag + (size_t)r * 36864, 4096,
                                                    meta, idx_map, dseg + r * 16, nullptr,
                                                    nullptr, cat, (r + 1) * 64, nullptr);
        stats_sorted<<<256, 512, 0, stream>>>(cat, (r + 1) * 64, meta,
                                              sums + r * 1024, sumsq + r * 1024);
        params_kernel<<<4, 256, 0, stream>>>(cnt, sums + r * 1024, sumsq + r * 1024,
                                             pA + r * 1024, pB + r * 1024);
        norm_sorted<<<8192, 256, 0, stream>>>(cat, (r + 1) * 64, meta,
                                              pA + r * 1024, pB + r * 1024);
      }
      conv_sorted<8, 1><<<1024, 256, 0, stream>>>(cat, wfrag + 110592, 16384,
                                                  meta, idx_map, nullptr, ord,
                                                  out, nullptr, 0, bf_);
    } else {
      for (int r = 0; r < 3; ++r) {
        conv_mfma<2, 0><<<1024, 256, 0, stream>>>(cat, 256, wfrag + (size_t)r * 36864, 4096,
                                                  indices, seg, idx_map, dseg + r * 16,
                                                  nullptr, cat, 256, (r + 1) * 64, nullptr);
        stats_kernel<<<256, 256, 0, stream>>>(cat, 256, (r + 1) * 64, seg,
                                              sums + r * 1024, sumsq + r * 1024);
        params_kernel<<<4, 256, 0, stream>>>(cnt, sums + r * 1024, sumsq + r * 1024,
                                             pA + r * 1024, pB + r * 1024);
        norm_kernel<<<16384, 256, 0, stream>>>(cat, 256, (r + 1) * 64, seg,
                                               pA + r * 1024, pB + r * 1024);
      }
      conv_mfma<8, 1><<<1024, 256, 0, stream>>>(cat, 256, wfrag + 110592, 16384,
                                                indices, seg, idx_map, nullptr,
                                                out, nullptr, 0, 0, bf_);
    }
  } else {
    bf16_t* feats_bf = (bf16_t*)(ws + 4194304);
    bf16_t* h_bf     = (bf16_t*)(ws + 37748864);
    bf16_t* wfrag    = (bf16_t*)(ws + 71303424);
    float*  stats    = (float*)(ws + 71819520);
    int* cnt  = (int*)stats;
    int* ymin = (int*)(stats + 16);
    int* ymax = (int*)(stats + 32);
    int* xmin = (int*)(stats + 48);
    int* xmax = (int*)(stats + 64);
    int* dseg = (int*)(stats + 80);
    float* sums  = stats + 128;
    float* sumsq = stats + 3200;
    float* pA    = stats + 6272;
    float* pB    = stats + 9344;

    hipMemsetAsync(feats_bf + (size_t)N_PTS * 64, 0, 128, stream);
    hipMemsetAsync(h_bf + (size_t)N_PTS * 64, 0, 128, stream);
    init_kernel<<<1, 256, 0, stream>>>(cnt, ymin, ymax, xmin, xmax, sums, sumsq, nullptr);
    scatter_kernel<<<N_PTS / 256, 256, 0, stream>>>(indices, seg, idx_map, cnt, ymin, ymax, xmin, xmax, nullptr);
    dilation_kernel<<<1, 64, 0, stream>>>(ymin, ymax, xmin, xmax, cnt, dseg);
    convert_kernel<<<16384, 256, 0, stream>>>((const float4*)feats, feats_bf, 64, nullptr);
    repack_kernel<<<1008, 256, 0, stream>>>(w1, w2, w3, wf, wfrag);

    conv_mfma<2, 1><<<1024, 256, 0, stream>>>(feats_bf, 64, wfrag + 110592, 16384,
                                              indices, seg, idx_map, nullptr,
                                              out, nullptr, 0, 0, bf_);
    for (int r = 0; r < 3; ++r) {
      conv_mfma<2, 0><<<1024, 256, 0, stream>>>(feats_bf, 64, wfrag + (size_t)r * 36864, 4096,
                                                indices, seg, idx_map, dseg + r * 16,
                                                nullptr, h_bf, 64, 0, nullptr);
      stats_kernel<<<256, 256, 0, stream>>>(h_bf, 64, 0, seg, sums + r * 1024, sumsq + r * 1024);
      params_kernel<<<4, 256, 0, stream>>>(cnt, sums + r * 1024, sumsq + r * 1024,
                                           pA + r * 1024, pB + r * 1024);
      norm_kernel<<<16384, 256, 0, stream>>>(h_bf, 64, 0, seg, pA + r * 1024, pB + r * 1024);
      conv_mfma<2, 2><<<1024, 256, 0, stream>>>(h_bf, 64, wfrag + 110592 + (size_t)(r + 1) * 4096, 16384,
                                                indices, seg, idx_map, nullptr,
                                                out, nullptr, 0, 0, nullptr);
    }
  }
}

// Round 6
// 589.584 us; speedup vs baseline: 1.7289x; 1.7282x over previous
//
#include <hip/hip_runtime.h>
#include <hip/hip_bf16.h>
#include <stdint.h>

#define N_PTS   262144
#define H_DIM   512
#define W_DIM   512
#define N_SEG   16
#define EPS_V   1e-5f

typedef __bf16 bf16_t;
typedef __bf16 bf16x8 __attribute__((ext_vector_type(8)));
typedef float  f32x4  __attribute__((ext_vector_type(4)));

// async global->LDS, 16B per lane. LDS dest must be wave-uniform base + lane*16.
__device__ __forceinline__ void gl_lds16(const bf16_t* g, bf16_t* l) {
  __builtin_amdgcn_global_load_lds(
      (const __attribute__((address_space(1))) unsigned int*)g,
      (__attribute__((address_space(3))) unsigned int*)l, 16, 0, 0);
}

// ------------- workspace layouts -------------
// T2 SORTED (ws >= 141.2 MB):
//   idx_map int[4*512*512]  @ 0          (seg<<18)|sorted_pos, -1 empty
//   cat     bf16[(N+1)*256] @ 4194304    SORTED rows: cat[pos] = point ord[pos]
//   wfrag   bf16[258048]    @ 138412544
//   stats   float[12416]    @ 138928640
//   hist    int[4096]       @ 138978304
//   cursor  int[4096]       @ 138994688
//   ord     int[N]          @ 139011072  sorted pos -> original idx
//   meta    int[N]          @ 140059648  (seg<<20)|(b<<18)|(y<<9)|x per sorted pos
// T1 FUSED (ws >= 139 MB): unsorted fallback
// T0 FALLBACK: 64-ch buffers at 72 MB.
// stats block (floats): cnt[16]@0 ymin@16 ymax@32 xmin@48 xmax@64 dseg[48]@80
//   sums[3*1024]@128 sumsq[3*1024]@3200 pA[3*1024]@6272 pB[3*1024]@9344

__global__ void init_kernel(int* cnt, int* ymin, int* ymax, int* xmin, int* xmax,
                            float* sums, float* sumsq, int* hist) {
  int t = threadIdx.x;
  if (t < N_SEG) {
    cnt[t] = 0;
    ymin[t] = 0x7fffffff; ymax[t] = (int)0x80000000;
    xmin[t] = 0x7fffffff; xmax[t] = (int)0x80000000;
  }
  for (int i = t; i < 3 * 1024; i += 256) { sums[i] = 0.f; sumsq[i] = 0.f; }
  if (hist) for (int i = t; i < 4096; i += 256) hist[i] = 0;
}

__global__ void scatter_kernel(const int* __restrict__ indices,
                               const int* __restrict__ seg,
                               int* __restrict__ idx_map,
                               int* __restrict__ cnt,
                               int* __restrict__ ymin, int* __restrict__ ymax,
                               int* __restrict__ xmin, int* __restrict__ xmax,
                               int* __restrict__ hist) {
  __shared__ int lc[N_SEG], ly0[N_SEG], ly1[N_SEG], lx0[N_SEG], lx1[N_SEG];
  int tid = threadIdx.x;
  if (tid < N_SEG) {
    lc[tid] = 0;
    ly0[tid] = 0x7fffffff; ly1[tid] = (int)0x80000000;
    lx0[tid] = 0x7fffffff; lx1[tid] = (int)0x80000000;
  }
  __syncthreads();
  int i = blockIdx.x * 256 + tid;
  int b = indices[i * 3], y = indices[i * 3 + 1], x = indices[i * 3 + 2];
  int s = seg[i];
  idx_map[(b * H_DIM + y) * W_DIM + x] = (s << 18) | i;   // T1 packing; T2 overwrites in rank
  atomicAdd(&lc[s], 1);
  atomicMin(&ly0[s], y); atomicMax(&ly1[s], y);
  atomicMin(&lx0[s], x); atomicMax(&lx1[s], x);
  if (hist) {
    int key = (b << 10) | ((y >> 4) << 5) | (x >> 4);     // 4096 spatial tiles
    atomicAdd(&hist[key], 1);
  }
  __syncthreads();
  if (tid < N_SEG && lc[tid] > 0) {
    atomicAdd(&cnt[tid], lc[tid]);
    atomicMin(&ymin[tid], ly0[tid]); atomicMax(&ymax[tid], ly1[tid]);
    atomicMin(&xmin[tid], lx0[tid]); atomicMax(&xmax[tid], lx1[tid]);
  }
}

// exclusive prefix sum of hist[4096] -> cursor[4096]
__global__ void scan_kernel(const int* __restrict__ hist, int* __restrict__ cursor) {
  __shared__ int s[256];
  int t = threadIdx.x;
  int base = t * 16;
  int loc[16];
  int acc = 0;
#pragma unroll
  for (int j = 0; j < 16; ++j) { loc[j] = acc; acc += hist[base + j]; }
  s[t] = acc;
  __syncthreads();
  for (int o = 1; o < 256; o <<= 1) {
    int v = (t >= o) ? s[t - o] : 0;
    __syncthreads();
    s[t] += v;
    __syncthreads();
  }
  int pre = (t == 0) ? 0 : s[t - 1];
#pragma unroll
  for (int j = 0; j < 16; ++j) cursor[base + j] = pre + loc[j];
}

// T2 rank: assigns sorted pos; writes ord, packed meta, and pos-packed idx_map
__global__ void rank_kernel(const int* __restrict__ indices,
                            const int* __restrict__ seg,
                            int* __restrict__ cursor, int* __restrict__ ord,
                            int* __restrict__ meta, int* __restrict__ idx_map) {
  int i = blockIdx.x * 256 + threadIdx.x;
  int b = indices[i * 3], y = indices[i * 3 + 1], x = indices[i * 3 + 2];
  int key = (b << 10) | ((y >> 4) << 5) | (x >> 4);
  int pos = atomicAdd(&cursor[key], 1);
  int s = seg[i];
  ord[pos] = i;
  meta[pos] = (s << 20) | (b << 18) | (y << 9) | x;
  idx_map[(b * H_DIM + y) * W_DIM + x] = (s << 18) | pos;
}

__global__ void dilation_kernel(const int* ymin, const int* ymax,
                                const int* xmin, const int* xmax,
                                const int* cnt, int* dseg) {
  int t = threadIdx.x;
  if (t < 48) {
    int r = t >> 4, s = t & 15;
    int rate = (r == 0) ? 1 : (r == 1) ? 3 : 5;
    int d = 1;
    if (cnt[s] > 0) {
      float hr = (float)(ymax[s] - ymin[s]) * (1.0f / H_DIM);
      float wr = (float)(xmax[s] - xmin[s]) * (1.0f / W_DIM);
      d = (int)ceilf(fmaxf(hr, wr) * (float)rate);
      if (d < 1) d = 1;
    }
    dseg[t] = d;
  }
}

// features fp32 -> bf16 rows; dst row pt <- src row (ord? ord[pt] : pt)
__global__ void convert_kernel(const float4* __restrict__ in, bf16_t* __restrict__ dst,
                               int stride, const int* __restrict__ ord) {
  int i = blockIdx.x * 256 + threadIdx.x;   // N*16
  int pt = i >> 4, g = i & 15;
  int sp = ord ? ord[pt] : pt;
  float4 v = in[(size_t)sp * 16 + g];
  union { bf16_t h[4]; uint2 u; } o;
  o.h[0] = (bf16_t)v.x; o.h[1] = (bf16_t)v.y;
  o.h[2] = (bf16_t)v.z; o.h[3] = (bf16_t)v.w;
  *(uint2*)(dst + (size_t)pt * stride + g * 4) = o.u;
}

// wfrag: [0,110592): branch r in {0,1,2} at r*36864, layout [k][kk2][cot][lane][j]
//        [110592,258048): fused final, layout [k][kk8][cot][lane][j], kk8=0..7
__global__ void repack_kernel(const float* __restrict__ w1, const float* __restrict__ w2,
                              const float* __restrict__ w3, const float* __restrict__ wf,
                              bf16_t* __restrict__ wfrag) {
  int e = blockIdx.x * 256 + threadIdx.x;   // < 258048
  if (e < 110592) {
    int s = e / 36864, rem = e % 36864;
    int k = rem >> 12, r2 = rem & 4095;
    int kk = r2 >> 11, r3 = r2 & 2047;
    int cot = r3 >> 9, r4 = r3 & 511;
    int lane = r4 >> 3, j = r4 & 7;
    int c  = kk * 32 + (lane >> 4) * 8 + j;
    int co = cot * 16 + (lane & 15);
    const float* w = (s == 0) ? w1 : (s == 1) ? w2 : w3;
    wfrag[e] = (bf16_t)w[k * 4096 + c * 64 + co];
  } else {
    int ef = e - 110592;
    int k = ef >> 14, r2 = ef & 16383;
    int kk8 = r2 >> 11, r3 = r2 & 2047;
    int cot = r3 >> 9, r4 = r3 & 511;
    int lane = r4 >> 3, j = r4 & 7;
    int c  = kk8 * 32 + (lane >> 4) * 8 + j;   // 0..255
    int co = cot * 16 + (lane & 15);
    wfrag[e] = (bf16_t)wf[k * 16384 + c * 64 + co];
  }
}

#define MF(ar, wr, i, j) \
  acc[i][j] = __builtin_amdgcn_mfma_f32_16x16x32_bf16(ar, wr, acc[i][j], 0, 0, 0)

// ============ T2 sorted conv ============
// cat rows are tile-sorted: a block's 256 points are rows [pt0, pt0+256) --
// contiguous. Block stages its OWN rows into LDS (coalesced global_load_lds,
// 16B-piece XOR swizzle via pre-swizzled global source); taps read LDS for
// in-block neighbors with masked global fallback. Outputs bounce through LDS
// to coalesced stores. Attacks per-CU vector-memory address throughput.
template <int KK, int MODE>
__launch_bounds__(256, 2)
__global__ void conv_sorted(const bf16_t* __restrict__ A,
                            const bf16_t* __restrict__ wfrag, int wkstride,
                            const int* __restrict__ meta,
                            const int* __restrict__ idx_map,
                            const int* __restrict__ dseg,
                            const int* __restrict__ ord,
                            float* __restrict__ outf,
                            bf16_t* __restrict__ outh, int hoff,
                            const float* __restrict__ bias) {
  __shared__ __align__(16) bf16_t s_a[256 * 64];   // 32 KB
  __shared__ __align__(16) bf16_t s_w[2][4096];    // 16 KB dbuf
  __shared__ int s_nbr[9 * 256];
  __shared__ int s_pt[256];
  const int tid = threadIdx.x;
  int bid = blockIdx.x;
  bid = (bid & 7) * ((int)gridDim.x >> 3) + (bid >> 3);   // XCD swizzle (1024%8==0)
  const int pt0 = bid * 256;

  // ---- setup: coalesced meta, spatially-local idx_map gathers ----
  {
    int mt = meta[pt0 + tid];
    if (MODE == 1) s_pt[tid] = ord[pt0 + tid];
    int sg = mt >> 20;
    int b = (mt >> 18) & 3, y = (mt >> 9) & 511, x = mt & 511;
    int d = (MODE == 0) ? dseg[sg] : 1;
#pragma unroll
    for (int k = 0; k < 9; ++k) {
      int ky = (k / 3) - 1, kx = (k % 3) - 1;
      int ny = y + ky * d, nx = x + kx * d;
      int e = N_PTS;                           // sentinel zero row
      if (ny >= 0 && ny < H_DIM && nx >= 0 && nx < W_DIM) {
        int v = idx_map[(b * H_DIM + ny) * W_DIM + nx];
        if (v >= 0) {
          int pos2 = v & 0x3FFFF;
          if (MODE == 0) { if ((v >> 18) == sg) e = pos2; }
          else e = pos2;
        }
      }
      unsigned lo = (unsigned)(e - pt0);
      s_nbr[k * 256 + tid] = (lo < 256u) ? -(int)(lo + 1) : e;   // neg = local slot
    }
  }

  const int lane = tid & 63;
  const int wv = tid >> 6;
  const int m = lane & 15;
  const int quad = lane >> 4;
  const int rb = wv * 64 + m;

  float b4[4];
  if (MODE == 1) {
#pragma unroll
    for (int cot = 0; cot < 4; ++cot) b4[cot] = bias[cot * 16 + m];
  }

  // stage own rows, quarter q (64ch = 8 x 16B pieces per row), piece-XOR-swizzled
  auto stageA = [&](int q) {
#pragma unroll
    for (int s = 0; s < 8; ++s) {
      int ch = s * 256 + tid;
      int r = ch >> 3, p = ch & 7;
      int ps = p ^ (r & 7);
      gl_lds16(A + (size_t)(pt0 + r) * 256 + q * 64 + ps * 8, &s_a[ch * 8]);
    }
  };
  auto stageW = [&](int k, int q, int buf) {
    const bf16_t* src = wfrag + (size_t)k * wkstride + q * 4096;
#pragma unroll
    for (int s = 0; s < 2; ++s) {
      int off = s * 2048 + tid * 8;
      gl_lds16(src + off, &s_w[buf][off]);
    }
  };

  f32x4 acc[4][4];
#pragma unroll
  for (int rt = 0; rt < 4; ++rt)
#pragma unroll
    for (int c = 0; c < 4; ++c) {
      acc[rt][c][0] = 0.f; acc[rt][c][1] = 0.f;
      acc[rt][c][2] = 0.f; acc[rt][c][3] = 0.f;
    }

  constexpr int NQ = (KK == 8) ? 4 : 1;
  for (int q = 0; q < NQ; ++q) {
    __syncthreads();                   // prev-quarter readers done / setup visible
    stageA(q);
    stageW(0, q, 0);
    __syncthreads();                   // drains vmcnt: s_a + s_w[0] ready
    int buf = 0;
    for (int k = 0; k < 9; ++k) {
      if (k < 8) stageW(k + 1, q, buf ^ 1);
      const int* sn = s_nbr + k * 256;
#pragma unroll
      for (int rt = 0; rt < 4; ++rt) {
        int e = sn[rb + rt * 16];
        bool loc = e < 0;
        int slot = loc ? (-e - 1) : 0;
        int grow = loc ? N_PTS : e;
        const bf16_t* gp = A + (size_t)grow * 256 + q * 64 + quad * 8;
        bf16x8 g0 = *(const bf16x8*)(gp);
        bf16x8 g1 = *(const bf16x8*)(gp + 32);
        int sw = slot & 7;
        bf16x8 l0 = *(const bf16x8*)&s_a[slot * 64 + ((quad ^ sw) << 3)];
        bf16x8 l1 = *(const bf16x8*)&s_a[slot * 64 + (((4 + quad) ^ sw) << 3)];
        bf16x8 a0 = loc ? l0 : g0;
        bf16x8 a1 = loc ? l1 : g1;
        const bf16_t* wl = &s_w[buf][lane * 8];
        MF(a0, *(const bf16x8*)(wl +    0), rt, 0);
        MF(a0, *(const bf16x8*)(wl +  512), rt, 1);
        MF(a0, *(const bf16x8*)(wl + 1024), rt, 2);
        MF(a0, *(const bf16x8*)(wl + 1536), rt, 3);
        MF(a1, *(const bf16x8*)(wl + 2048), rt, 0);
        MF(a1, *(const bf16x8*)(wl + 2560), rt, 1);
        MF(a1, *(const bf16x8*)(wl + 3072), rt, 2);
        MF(a1, *(const bf16x8*)(wl + 3584), rt, 3);
      }
      __syncthreads();                 // all done with s_w[buf]; next stage landed
      buf ^= 1;
    }
  }

  // ---- epilogue via LDS bounce -> coalesced stores ----
  if (MODE == 0) {
#pragma unroll
    for (int rt = 0; rt < 4; ++rt)
#pragma unroll
      for (int reg = 0; reg < 4; ++reg) {
        int row = wv * 64 + rt * 16 + quad * 4 + reg;
#pragma unroll
        for (int cot = 0; cot < 4; ++cot) {
          int col = cot * 16 + m;
          int p = col >> 3;
          s_a[row * 64 + (((p ^ (row & 7)) << 3) | (col & 7))] = (bf16_t)acc[rt][cot][reg];
        }
      }
    __syncthreads();
#pragma unroll
    for (int s = 0; s < 8; ++s) {
      int g = s * 256 + tid;
      int r = g >> 3, p = g & 7;
      uint4 v = *(const uint4*)&s_a[r * 64 + ((p ^ (r & 7)) << 3)];
      *(uint4*)(outh + (size_t)(pt0 + r) * 256 + hoff + p * 8) = v;
    }
  } else {
    float* s_af = (float*)s_a;         // 256 x 32 f32 per half
#pragma unroll
    for (int hh = 0; hh < 2; ++hh) {
      if (hh) __syncthreads();
#pragma unroll
      for (int rt = 0; rt < 4; ++rt)
#pragma unroll
        for (int reg = 0; reg < 4; ++reg) {
          int row = wv * 64 + rt * 16 + quad * 4 + reg;
#pragma unroll
          for (int c2 = 0; c2 < 2; ++c2) {
            int cot = hh * 2 + c2;
            int col32 = c2 * 16 + m;
            int p = col32 >> 2;
            s_af[row * 32 + (((p ^ (row & 7)) << 2) | (col32 & 3))] =
                acc[rt][cot][reg] + b4[cot];
          }
        }
      __syncthreads();
#pragma unroll
      for (int s = 0; s < 8; ++s) {
        int g = s * 256 + tid;
        int r = g >> 3, p = g & 7;
        float4 v = *(const float4*)&s_af[r * 32 + ((p ^ (r & 7)) << 2)];
        *(float4*)(outf + (size_t)s_pt[r] * 64 + hh * 32 + p * 4) = v;
      }
    }
  }
}

// ============ T1/T0 conv (round-3 version, unsorted-safe) ============
template <int KK, int MODE>
__launch_bounds__(256, 3)
__global__ void conv_mfma(const bf16_t* __restrict__ A, int astride,
                          const bf16_t* __restrict__ wfrag, int wkstride,
                          const int* __restrict__ indices,
                          const int* __restrict__ seg,
                          const int* __restrict__ idx_map,
                          const int* __restrict__ dseg,
                          float* __restrict__ outf,
                          bf16_t* __restrict__ outh, int hstride, int hoff,
                          const float* __restrict__ bias) {
  constexpr int WELEM = (KK == 8) ? 8192 : 4096;
  constexpr int SWEEPS = (KK == 8) ? 4 : 2;
  __shared__ int s_nbr[9 * 256];
  __shared__ __align__(16) bf16_t s_w[2][WELEM];
  const int tid = threadIdx.x;
  const int pt0 = blockIdx.x * 256;

  {
    int pt = pt0 + tid;
    int b = indices[pt * 3], y = indices[pt * 3 + 1], x = indices[pt * 3 + 2];
    int sg = 0, d = 1;
    if (MODE == 0) { sg = seg[pt]; d = dseg[sg]; }
#pragma unroll
    for (int k = 0; k < 9; ++k) {
      int ky = (k / 3) - 1, kx = (k % 3) - 1;
      int ny = y + ky * d, nx = x + kx * d;
      int nbr = N_PTS;
      if (ny >= 0 && ny < H_DIM && nx >= 0 && nx < W_DIM) {
        int v = idx_map[(b * H_DIM + ny) * W_DIM + nx];
        if (v >= 0) {
          if (MODE == 0) nbr = ((v >> 18) == sg) ? (v & 0x3FFFF) : N_PTS;
          else           nbr = v & 0x3FFFF;
        }
      }
      s_nbr[k * 256 + tid] = nbr;
    }
  }

  auto stage = [&](int ph, int buf) {
    const bf16_t* src;
    if constexpr (KK == 8) src = wfrag + (size_t)(ph >> 1) * wkstride + (ph & 1) * 8192;
    else                   src = wfrag + (size_t)ph * wkstride;
#pragma unroll
    for (int s = 0; s < SWEEPS; ++s) {
      int off = s * 2048 + tid * 8;
      gl_lds16(src + off, &s_w[buf][off]);
    }
  };

  stage(0, 0);
  __syncthreads();

  const int lane = tid & 63;
  const int wv = tid >> 6;
  const int m = lane & 15;
  const int quad = lane >> 4;
  const int rbase = wv * 64 + m;

  f32x4 acc[4][4];
#pragma unroll
  for (int rt = 0; rt < 4; ++rt)
#pragma unroll
    for (int c = 0; c < 4; ++c) {
      acc[rt][c][0] = 0.f; acc[rt][c][1] = 0.f;
      acc[rt][c][2] = 0.f; acc[rt][c][3] = 0.f;
    }

#define MF16X(A0, A1, A2, A3, W0, W1, W2, W3) \
  MF(A0, W0, 0, 0); MF(A0, W1, 0, 1); MF(A0, W2, 0, 2); MF(A0, W3, 0, 3); \
  MF(A1, W0, 1, 0); MF(A1, W1, 1, 1); MF(A1, W2, 1, 2); MF(A1, W3, 1, 3); \
  MF(A2, W0, 2, 0); MF(A2, W1, 2, 1); MF(A2, W2, 2, 2); MF(A2, W3, 2, 3); \
  MF(A3, W0, 3, 0); MF(A3, W1, 3, 1); MF(A3, W2, 3, 2); MF(A3, W3, 3, 3)

  if constexpr (KK == 2) {
    for (int k = 0; k < 9; ++k) {
      const int cur = k & 1;
      if (k < 8) stage(k + 1, cur ^ 1);
      const int* sn = s_nbr + k * 256 + rbase;
      const bf16_t* a0p = A + (size_t)sn[0]  * astride + quad * 8;
      const bf16_t* a1p = A + (size_t)sn[16] * astride + quad * 8;
      const bf16_t* a2p = A + (size_t)sn[32] * astride + quad * 8;
      const bf16_t* a3p = A + (size_t)sn[48] * astride + quad * 8;
      bf16x8 a00 = *(const bf16x8*)(a0p), a01 = *(const bf16x8*)(a0p + 32);
      bf16x8 a10 = *(const bf16x8*)(a1p), a11 = *(const bf16x8*)(a1p + 32);
      bf16x8 a20 = *(const bf16x8*)(a2p), a21 = *(const bf16x8*)(a2p + 32);
      bf16x8 a30 = *(const bf16x8*)(a3p), a31 = *(const bf16x8*)(a3p + 32);
      const bf16_t* wl = &s_w[cur][lane * 8];
      bf16x8 w00 = *(const bf16x8*)(wl +    0), w01 = *(const bf16x8*)(wl +  512);
      bf16x8 w02 = *(const bf16x8*)(wl + 1024), w03 = *(const bf16x8*)(wl + 1536);
      bf16x8 w10 = *(const bf16x8*)(wl + 2048), w11 = *(const bf16x8*)(wl + 2560);
      bf16x8 w12 = *(const bf16x8*)(wl + 3072), w13 = *(const bf16x8*)(wl + 3584);
      MF16X(a00, a10, a20, a30, w00, w01, w02, w03);
      MF16X(a01, a11, a21, a31, w10, w11, w12, w13);
      __syncthreads();
    }
  } else {
    for (int h = 0; h < 18; ++h) {
      const int cur = h & 1;
      if (h < 17) stage(h + 1, cur ^ 1);
      const int k = h >> 1;
      const int colb = (h & 1) * 128;
      const int* sn = s_nbr + k * 256 + rbase;
      const bf16_t* a0p = A + (size_t)sn[0]  * astride + quad * 8 + colb;
      const bf16_t* a1p = A + (size_t)sn[16] * astride + quad * 8 + colb;
      const bf16_t* a2p = A + (size_t)sn[32] * astride + quad * 8 + colb;
      const bf16_t* a3p = A + (size_t)sn[48] * astride + quad * 8 + colb;
#pragma unroll
      for (int kp = 0; kp < 2; ++kp) {
        const int cb = kp * 64;
        bf16x8 a00 = *(const bf16x8*)(a0p + cb), a01 = *(const bf16x8*)(a0p + cb + 32);
        bf16x8 a10 = *(const bf16x8*)(a1p + cb), a11 = *(const bf16x8*)(a1p + cb + 32);
        bf16x8 a20 = *(const bf16x8*)(a2p + cb), a21 = *(const bf16x8*)(a2p + cb + 32);
        bf16x8 a30 = *(const bf16x8*)(a3p + cb), a31 = *(const bf16x8*)(a3p + cb + 32);
        const bf16_t* wl = &s_w[cur][kp * 4096 + lane * 8];
        bf16x8 w00 = *(const bf16x8*)(wl +    0), w01 = *(const bf16x8*)(wl +  512);
        bf16x8 w02 = *(const bf16x8*)(wl + 1024), w03 = *(const bf16x8*)(wl + 1536);
        bf16x8 w10 = *(const bf16x8*)(wl + 2048), w11 = *(const bf16x8*)(wl + 2560);
        bf16x8 w12 = *(const bf16x8*)(wl + 3072), w13 = *(const bf16x8*)(wl + 3584);
        MF16X(a00, a10, a20, a30, w00, w01, w02, w03);
        MF16X(a01, a11, a21, a31, w10, w11, w12, w13);
      }
      __syncthreads();
    }
  }

#pragma unroll
  for (int rt = 0; rt < 4; ++rt) {
#pragma unroll
    for (int reg = 0; reg < 4; ++reg) {
      int pt = pt0 + wv * 64 + rt * 16 + quad * 4 + reg;
#pragma unroll
      for (int cot = 0; cot < 4; ++cot) {
        int col = cot * 16 + m;
        float v = acc[rt][cot][reg];
        if (MODE == 0)      outh[(size_t)pt * hstride + hoff + col] = (bf16_t)v;
        else if (MODE == 1) outf[(size_t)pt * 64 + col] = v + bias[col];
        else                outf[(size_t)pt * 64 + col] += v;
      }
    }
  }
}

// T1/T0 stats (requires seg sorted over row index — original order)
__global__ void stats_kernel(const bf16_t* __restrict__ h, int stride, int off,
                             const int* __restrict__ seg,
                             float* __restrict__ sums, float* __restrict__ sumsq) {
  int tid = threadIdx.x;
  int co = tid & 63, pr = tid >> 6;
  int base = blockIdx.x * 1024;
  float s = 0.f, s2 = 0.f;
  int cur = seg[base];
  for (int i = pr; i < 1024; i += 4) {
    int pt = base + i;
    int sg = seg[pt];
    float v = (float)h[(size_t)pt * stride + off + co];
    if (sg != cur) {
      atomicAdd(&sums[cur * 64 + co], s);
      atomicAdd(&sumsq[cur * 64 + co], s2);
      s = 0.f; s2 = 0.f; cur = sg;
    }
    s += v; s2 += v * v;
  }
  atomicAdd(&sums[cur * 64 + co], s);
  atomicAdd(&sumsq[cur * 64 + co], s2);
}

// T2 stats v3. Rounds 4 AND 5 were LDS-atomic-throughput-bound: both issued
// 1024 rows x 64 ch x 2 = 131K LDS atomic lane-ops/block (~3.3 cy each = 180us
// at 1 block/CU), regardless of contention pattern. v3 eliminates per-element
// atomics: bucket rows by seg into a perm list (seg-sorted runs), then each
// wave register-accumulates its 128-row chunk (lane = channel, one coalesced
// 128B line per row, 4-deep load pipeline) and flushes to LDS bins only on
// wave-uniform seg change (~16 flushes/wave instead of per-element).
__global__ void __launch_bounds__(512)
stats_sorted(const bf16_t* __restrict__ h, int off,
             const int* __restrict__ meta,
             float* __restrict__ sums, float* __restrict__ sumsq) {
  __shared__ float bs[1024], bq[1024];
  __shared__ unsigned short perm[1024];
  __shared__ unsigned char ssg[1024];
  __shared__ int cnt16[16], cur16[16];
  const int tid = threadIdx.x;
  const int base = blockIdx.x * 1024;
  if (tid < 16) cnt16[tid] = 0;
  for (int i = tid; i < 1024; i += 512) { bs[i] = 0.f; bq[i] = 0.f; }
  __syncthreads();
  // phase 1: seg per row + 16-bin histogram (cheap: 1024 atomics on 16 ctrs)
  for (int i = tid; i < 1024; i += 512) {
    int sg = meta[base + i] >> 20;
    ssg[i] = (unsigned char)sg;
    atomicAdd(&cnt16[sg], 1);
  }
  __syncthreads();
  // phase 2: serial 16-wide exclusive scan
  if (tid == 0) {
    int acc = 0;
    for (int s = 0; s < 16; ++s) { cur16[s] = acc; acc += cnt16[s]; }
  }
  __syncthreads();
  // phase 3: scatter row ids into seg-sorted perm
  for (int i = tid; i < 1024; i += 512) {
    int p = atomicAdd(&cur16[ssg[i]], 1);
    perm[p] = (unsigned short)i;
  }
  __syncthreads();
  // phase 4: 8 waves x 128 perm rows; lane = channel; register accumulation
  const int wv = tid >> 6, lane = tid & 63;
  const int i0 = wv * 128;
  const bf16_t* hb = h + off + lane;
  int pbuf[4]; float vbuf[4];
#pragma unroll
  for (int j = 0; j < 4; ++j) {
    pbuf[j] = perm[i0 + j];
    vbuf[j] = (float)hb[(size_t)(base + pbuf[j]) * 256];
  }
  float s = 0.f, s2 = 0.f;
  int cur = ssg[pbuf[0]];
  for (int i = 0; i < 128; i += 4) {
    const bool more = (i + 4 < 128);
    int pn[4]; float vn[4];
    if (more) {
#pragma unroll
      for (int j = 0; j < 4; ++j) {
        pn[j] = perm[i0 + i + 4 + j];
        vn[j] = (float)hb[(size_t)(base + pn[j]) * 256];   // in flight over process
      }
    }
#pragma unroll
    for (int j = 0; j < 4; ++j) {
      int sg = ssg[pbuf[j]];                // wave-uniform (runs in perm)
      if (sg != cur) {
        atomicAdd(&bs[cur * 64 + lane], s);
        atomicAdd(&bq[cur * 64 + lane], s2);
        s = 0.f; s2 = 0.f; cur = sg;
      }
      s += vbuf[j]; s2 += vbuf[j] * vbuf[j];
    }
    if (more) {
#pragma unroll
      for (int j = 0; j < 4; ++j) { pbuf[j] = pn[j]; vbuf[j] = vn[j]; }
    }
  }
  atomicAdd(&bs[cur * 64 + lane], s);
  atomicAdd(&bq[cur * 64 + lane], s2);
  __syncthreads();
  // phase 5: block bins -> global
  for (int i = tid; i < 1024; i += 512) {
    atomicAdd(&sums[i], bs[i]);
    atomicAdd(&sumsq[i], bq[i]);
  }
}

__global__ void params_kernel(const int* __restrict__ cnt, const float* __restrict__ sums,
                              const float* __restrict__ sumsq,
                              float* __restrict__ pA, float* __restrict__ pB) {
  int t = blockIdx.x * 256 + threadIdx.x;
  if (t < 1024) {
    int sgi = t >> 6;
    float c = (float)cnt[sgi];
    float a = 0.f, b = 0.f;
    if (c > 0.f) {
      float mean = sums[t] / c;
      float var = sumsq[t] / c - mean * mean;
      float inv = rsqrtf(var + EPS_V);
      a = inv; b = -mean * inv;
    }
    pA[t] = a; pB[t] = b;
  }
}

__global__ void norm_kernel(bf16_t* __restrict__ h, int stride, int off,
                            const int* __restrict__ seg,
                            const float* __restrict__ pA, const float* __restrict__ pB) {
  int i = blockIdx.x * 256 + threadIdx.x;   // N*16
  int pt = i >> 4;
  int cg = (i & 15) * 4;
  int sg = seg[pt];
  bf16_t* p = h + (size_t)pt * stride + off + cg;
  union { bf16_t hh[4]; uint2 u; } v;
  v.u = *(uint2*)p;
#pragma unroll
  for (int j = 0; j < 4; ++j) {
    float f = (float)v.hh[j] * pA[sg * 64 + cg + j] + pB[sg * 64 + cg + j];
    v.hh[j] = (bf16_t)fmaxf(f, 0.f);
  }
  *(uint2*)p = v.u;
}

// T2 norm: 8ch per thread, float4 param loads
__global__ void norm_sorted(bf16_t* __restrict__ h, int off,
                            const int* __restrict__ meta,
                            const float* __restrict__ pA, const float* __restrict__ pB) {
  int i = blockIdx.x * 256 + threadIdx.x;   // N*8
  int pt = i >> 3;
  int cg = (i & 7) * 8;
  int sg = meta[pt] >> 20;
  bf16_t* p = h + (size_t)pt * 256 + off + cg;
  union { bf16_t hh[8]; uint4 u; } v;
  v.u = *(uint4*)p;
  float4 a0 = *(const float4*)&pA[sg * 64 + cg];
  float4 a1 = *(const float4*)&pA[sg * 64 + cg + 4];
  float4 b0 = *(const float4*)&pB[sg * 64 + cg];
  float4 b1 = *(const float4*)&pB[sg * 64 + cg + 4];
  float av[8] = {a0.x, a0.y, a0.z, a0.w, a1.x, a1.y, a1.z, a1.w};
  float bv[8] = {b0.x, b0.y, b0.z, b0.w, b1.x, b1.y, b1.z, b1.w};
#pragma unroll
  for (int j = 0; j < 8; ++j) {
    float f = (float)v.hh[j] * av[j] + bv[j];
    v.hh[j] = (bf16_t)fmaxf(f, 0.f);
  }
  *(uint4*)p = v.u;
}

extern "C" void kernel_launch(void* const* d_in, const int* in_sizes, int n_in,
                              void* d_out, int out_size, void* d_ws, size_t ws_size,
                              hipStream_t stream) {
  const float* feats   = (const float*)d_in[0];
  const int*   indices = (const int*)d_in[1];
  const int*   seg     = (const int*)d_in[2];
  const float* w1 = (const float*)d_in[3];
  const float* w2 = (const float*)d_in[5];
  const float* w3 = (const float*)d_in[7];
  const float* wf = (const float*)d_in[9];
  const float* bf_ = (const float*)d_in[10];
  float* out = (float*)d_out;

  char* ws = (char*)d_ws;
  const bool t2 = (ws_size >= 141200000ull);
  const bool fused = t2 || (ws_size >= 139000000ull);

  int* idx_map = (int*)(ws + 0);
  hipMemsetAsync(idx_map, 0xFF, 4194304, stream);

  if (fused) {
    bf16_t* cat   = (bf16_t*)(ws + 4194304);
    bf16_t* wfrag = (bf16_t*)(ws + 138412544);
    float*  stats = (float*)(ws + 138928640);
    int* cnt  = (int*)stats;
    int* ymin = (int*)(stats + 16);
    int* ymax = (int*)(stats + 32);
    int* xmin = (int*)(stats + 48);
    int* xmax = (int*)(stats + 64);
    int* dseg = (int*)(stats + 80);
    float* sums  = stats + 128;
    float* sumsq = stats + 3200;
    float* pA    = stats + 6272;
    float* pB    = stats + 9344;
    int* hist   = t2 ? (int*)(ws + 138978304) : nullptr;
    int* cursor = t2 ? (int*)(ws + 138994688) : nullptr;
    int* ord    = t2 ? (int*)(ws + 139011072) : nullptr;
    int* meta   = t2 ? (int*)(ws + 140059648) : nullptr;

    hipMemsetAsync(cat + (size_t)N_PTS * 256, 0, 512, stream);   // sentinel row
    init_kernel<<<1, 256, 0, stream>>>(cnt, ymin, ymax, xmin, xmax, sums, sumsq, hist);
    scatter_kernel<<<N_PTS / 256, 256, 0, stream>>>(indices, seg, idx_map, cnt, ymin, ymax, xmin, xmax, hist);
    dilation_kernel<<<1, 64, 0, stream>>>(ymin, ymax, xmin, xmax, cnt, dseg);
    if (t2) {
      scan_kernel<<<1, 256, 0, stream>>>(hist, cursor);
      rank_kernel<<<N_PTS / 256, 256, 0, stream>>>(indices, seg, cursor, ord, meta, idx_map);
    }
    convert_kernel<<<16384, 256, 0, stream>>>((const float4*)feats, cat, 256, ord);
    repack_kernel<<<1008, 256, 0, stream>>>(w1, w2, w3, wf, wfrag);

    if (t2) {
      for (int r = 0; r < 3; ++r) {
        conv_sorted<2, 0><<<1024, 256, 0, stream>>>(cat, wfrag + (size_t)r * 36864, 4096,
                                                    meta, idx_map, dseg + r * 16, nullptr,
                                                    nullptr, cat, (r + 1) * 64, nullptr);
        stats_sorted<<<256, 512, 0, stream>>>(cat, (r + 1) * 64, meta,
                                              sums + r * 1024, sumsq + r * 1024);
        params_kernel<<<4, 256, 0, stream>>>(cnt, sums + r * 1024, sumsq + r * 1024,
                                             pA + r * 1024, pB + r * 1024);
        norm_sorted<<<8192, 256, 0, stream>>>(cat, (r + 1) * 64, meta,
                                              pA + r * 1024, pB + r * 1024);
      }
      conv_sorted<8, 1><<<1024, 256, 0, stream>>>(cat, wfrag + 110592, 16384,
                                                  meta, idx_map, nullptr, ord,
                                                  out, nullptr, 0, bf_);
    } else {
      for (int r = 0; r < 3; ++r) {
        conv_mfma<2, 0><<<1024, 256, 0, stream>>>(cat, 256, wfrag + (size_t)r * 36864, 4096,
                                                  indices, seg, idx_map, dseg + r * 16,
                                                  nullptr, cat, 256, (r + 1) * 64, nullptr);
        stats_kernel<<<256, 256, 0, stream>>>(cat, 256, (r + 1) * 64, seg,
                                              sums + r * 1024, sumsq + r * 1024);
        params_kernel<<<4, 256, 0, stream>>>(cnt, sums + r * 1024, sumsq + r * 1024,
                                             pA + r * 1024, pB + r * 1024);
        norm_kernel<<<16384, 256, 0, stream>>>(cat, 256, (r + 1) * 64, seg,
                                               pA + r * 1024, pB + r * 1024);
      }
      conv_mfma<8, 1><<<1024, 256, 0, stream>>>(cat, 256, wfrag + 110592, 16384,
                                                indices, seg, idx_map, nullptr,
                                                out, nullptr, 0, 0, bf_);
    }
  } else {
    bf16_t* feats_bf = (bf16_t*)(ws + 4194304);
    bf16_t* h_bf     = (bf16_t*)(ws + 37748864);
    bf16_t* wfrag    = (bf16_t*)(ws + 71303424);
    float*  stats    = (float*)(ws + 71819520);
    int* cnt  = (int*)stats;
    int* ymin = (int*)(stats + 16);
    int* ymax = (int*)(stats + 32);
    int* xmin = (int*)(stats + 48);
    int* xmax = (int*)(stats + 64);
    int* dseg = (int*)(stats + 80);
    float* sums  = stats + 128;
    float* sumsq = stats + 3200;
    float* pA    = stats + 6272;
    float* pB    = stats + 9344;

    hipMemsetAsync(feats_bf + (size_t)N_PTS * 64, 0, 128, stream);
    hipMemsetAsync(h_bf + (size_t)N_PTS * 64, 0, 128, stream);
    init_kernel<<<1, 256, 0, stream>>>(cnt, ymin, ymax, xmin, xmax, sums, sumsq, nullptr);
    scatter_kernel<<<N_PTS / 256, 256, 0, stream>>>(indices, seg, idx_map, cnt, ymin, ymax, xmin, xmax, nullptr);
    dilation_kernel<<<1, 64, 0, stream>>>(ymin, ymax, xmin, xmax, cnt, dseg);
    convert_kernel<<<16384, 256, 0, stream>>>((const float4*)feats, feats_bf, 64, nullptr);
    repack_kernel<<<1008, 256, 0, stream>>>(w1, w2, w3, wf, wfrag);

    conv_mfma<2, 1><<<1024, 256, 0, stream>>>(feats_bf, 64, wfrag + 110592, 16384,
                                              indices, seg, idx_map, nullptr,
                                              out, nullptr, 0, 0, bf_);
    for (int r = 0; r < 3; ++r) {
      conv_mfma<2, 0><<<1024, 256, 0, stream>>>(feats_bf, 64, wfrag + (size_t)r * 36864, 4096,
                                                indices, seg, idx_map, dseg + r * 16,
                                                nullptr, h_bf, 64, 0, nullptr);
      stats_kernel<<<256, 256, 0, stream>>>(h_bf, 64, 0, seg, sums + r * 1024, sumsq + r * 1024);
      params_kernel<<<4, 256, 0, stream>>>(cnt, sums + r * 1024, sumsq + r * 1024,
                                           pA + r * 1024, pB + r * 1024);
      norm_kernel<<<16384, 256, 0, stream>>>(h_bf, 64, 0, seg, pA + r * 1024, pB + r * 1024);
      conv_mfma<2, 2><<<1024, 256, 0, stream>>>(h_bf, 64, wfrag + 110592 + (size_t)(r + 1) * 4096, 16384,
                                                indices, seg, idx_map, nullptr,
                                                out, nullptr, 0, 0, nullptr);
    }
  }
}